// Round 12
// baseline (1316.851 us; speedup 1.0000x reference)
//
#include <hip/hip_runtime.h>
#include <hip/hip_bf16.h>
#include <type_traits>

// ---------------------------------------------------------------------------
// ROLAND GNN forward. Buffers f32; matmuls bf16-MFMA, f32 accum.
// Outputs (concat, f32): logits[EL], emb0[N,128], emb1[N,128], emb2[N,128]
// Round 12: gg_kernel v2 -- edge-balanced gather (contiguous CSR range per
// 64-row block, LDS f32-atomic accumulation, zero divergence), hacc LDS
// aliased as the GRU weight buffer. rowptr is N+1; fill records csr_dst.
// ---------------------------------------------------------------------------

typedef __bf16 bf16;
typedef __bf16 bf16x8 __attribute__((ext_vector_type(8)));
typedef float  f32x4  __attribute__((ext_vector_type(4)));

#define DEV __device__ __forceinline__

DEV f32x4 mfma16(bf16x8 a, bf16x8 b, f32x4 c) {
    return __builtin_amdgcn_mfma_f32_16x16x32_bf16(a, b, c, 0, 0, 0);
}

DEV bf16x8 load_a8(const float* p) {
    f32x4 lo = *(const f32x4*)p;
    f32x4 hi = *(const f32x4*)(p + 4);
    bf16x8 v;
    v[0] = (bf16)lo[0]; v[1] = (bf16)lo[1]; v[2] = (bf16)lo[2]; v[3] = (bf16)lo[3];
    v[4] = (bf16)hi[0]; v[5] = (bf16)hi[1]; v[6] = (bf16)hi[2]; v[7] = (bf16)hi[3];
    return v;
}
DEV bf16x8 load_a8(const bf16* p) { return *(const bf16x8*)p; }

// single fused f32->bf16 conversion of all 8 weight matrices into wb
__global__ void cvt8_kernel(const float* s0, const float* s1, const float* s2, const float* s3,
                            const float* s4, const float* s5, const float* s6, const float* s7,
                            bf16* __restrict__ wb) {
    const int i = blockIdx.x * 256 + threadIdx.x;
    if (i >= 294912) return;
    float v;
    if      (i < 32768)  v = s0[i];
    else if (i < 65536)  v = s1[i - 32768];
    else if (i < 81920)  v = s2[i - 65536];
    else if (i < 98304)  v = s3[i - 81920];
    else if (i < 147456) v = s4[i - 98304];
    else if (i < 196608) v = s5[i - 147456];
    else if (i < 245760) v = s6[i - 196608];
    else                 v = s7[i - 245760];
    wb[i] = (bf16)v;
}

// ---------------------------------------------------------------------------
// GEMM: C[M,Co] = act(A[M,Ci] @ W[Co,Ci]^T + bias). 2 M-tiles/wave.
// ---------------------------------------------------------------------------
template<int Ci, int Co, bool ACT, bool BIAS, typename AT, typename OT>
__global__ __launch_bounds__(256) void gemm_kernel(
    const AT* __restrict__ A, const bf16* __restrict__ W,
    const float* __restrict__ bias, OT* __restrict__ C, int M)
{
    const int tid  = threadIdx.x;
    const int lane = tid & 63, w = tid >> 6;
    const int lr   = lane & 15, ko = lane >> 4;
    const int rbase = blockIdx.x * 128 + w * 32;

    constexpr int KC = Ci / 32;
    constexpr int NT = Co / 16;

    bf16x8 a[2][KC];
#pragma unroll
    for (int m = 0; m < 2; ++m) {
        long arow = rbase + m * 16 + lr; if (arow > M - 1) arow = M - 1;  // clamped rows never stored
#pragma unroll
        for (int kc = 0; kc < KC; ++kc)
            a[m][kc] = load_a8(A + arow * Ci + kc * 32 + ko * 8);
    }

#pragma unroll
    for (int t = 0; t < NT; ++t) {
        f32x4 acc0 = {0.f, 0.f, 0.f, 0.f};
        f32x4 acc1 = {0.f, 0.f, 0.f, 0.f};
        const bf16* wp = W + (long)(t * 16 + lr) * Ci + ko * 8;
#pragma unroll
        for (int kc = 0; kc < KC; ++kc) {
            bf16x8 wf = *(const bf16x8*)(wp + kc * 32);
            acc0 = mfma16(a[0][kc], wf, acc0);
            acc1 = mfma16(a[1][kc], wf, acc1);
        }

        const int col = t * 16 + lr;
        float bv = 0.f;
        if (BIAS) bv = bias[col];
#pragma unroll
        for (int j = 0; j < 4; ++j) {
            const int r0 = rbase + ko * 4 + j;
            if (r0 < M) {
                float v = acc0[j] + bv;
                if (ACT) v = (v >= 0.f) ? v : 0.01f * v;
                C[(long)r0 * Co + col] = (OT)v;
            }
            const int r1 = rbase + 16 + ko * 4 + j;
            if (r1 < M) {
                float v = acc1[j] + bv;
                if (ACT) v = (v >= 0.f) ? v : 0.01f * v;
                C[(long)r1 * Co + col] = (OT)v;
            }
        }
    }
}

// ---------------------------------------------------------------------------
// GRUCell, 64-row blocks (4 waves x 16 rows), LDS weight tiles + reg prefetch.
// Safe for out == x (f32 path): all A-frag reads precede the first barrier.
// ---------------------------------------------------------------------------
template<typename XT>
__global__ __launch_bounds__(256) void gru_kernel(
    const XT* x, const float* __restrict__ hp,
    const bf16* __restrict__ wih, const bf16* __restrict__ whh,
    const float* __restrict__ bih, const float* __restrict__ bhh,
    float* out, int N)
{
    __shared__ bf16 Lw[6][16][128];   // 24 KB

    const int tid  = threadIdx.x;
    const int lane = tid & 63, w = tid >> 6;
    const int lr   = lane & 15, ko = lane >> 4;
    const long rbase = (long)blockIdx.x * 64 + w * 16;

    long arow = rbase + lr; if (arow > N - 1) arow = N - 1;
    bf16x8 ax[4], ah[4];
#pragma unroll
    for (int kc = 0; kc < 4; ++kc) {
        ax[kc] = load_a8(x  + arow * 128 + kc * 32 + ko * 8);
        ah[kc] = load_a8(hp + arow * 128 + kc * 32 + ko * 8);
    }

    bf16x8 pre[6];
    auto LDW = [&](int tc) {
#pragma unroll
        for (int i = 0; i < 6; ++i) {
            const int ch  = tid + 256 * i;
            const int g   = ch >> 8, rem = ch & 255;
            const int row = rem >> 4, cc = rem & 15;
            const int scc = cc ^ (row & 7);
            pre[i] = *(const bf16x8*)((g < 3 ? wih : whh)
                + (long)(((g % 3) * 128 + tc * 16 + row) * 128 + scc * 8));
        }
    };
    LDW(0);

    for (int tc = 0; tc < 8; ++tc) {
        __syncthreads();
#pragma unroll
        for (int i = 0; i < 6; ++i) {
            const int ch  = tid + 256 * i;
            const int g   = ch >> 8, rem = ch & 255;
            const int row = rem >> 4, cc = rem & 15;
            *(bf16x8*)(&Lw[g][row][cc * 8]) = pre[i];
        }
        __syncthreads();
        if (tc < 7) LDW(tc + 1);

        const int col = tc * 16 + lr;
        const float br = bih[col]       + bhh[col];
        const float bz = bih[128 + col] + bhh[128 + col];
        const float bi = bih[256 + col];
        const float bh = bhh[256 + col];

        f32x4 ar = {0.f, 0.f, 0.f, 0.f};
        f32x4 az = {0.f, 0.f, 0.f, 0.f};
        f32x4 ai = {0.f, 0.f, 0.f, 0.f};
        f32x4 ag = {0.f, 0.f, 0.f, 0.f};
#pragma unroll
        for (int kc = 0; kc < 4; ++kc) {
            const int cc = (kc * 4 + ko) ^ (lr & 7);
            bf16x8 wr_i = *(const bf16x8*)(&Lw[0][lr][cc * 8]);
            bf16x8 wz_i = *(const bf16x8*)(&Lw[1][lr][cc * 8]);
            bf16x8 wn_i = *(const bf16x8*)(&Lw[2][lr][cc * 8]);
            bf16x8 wr_h = *(const bf16x8*)(&Lw[3][lr][cc * 8]);
            bf16x8 wz_h = *(const bf16x8*)(&Lw[4][lr][cc * 8]);
            bf16x8 wn_h = *(const bf16x8*)(&Lw[5][lr][cc * 8]);
            ar = mfma16(ax[kc], wr_i, ar);
            ar = mfma16(ah[kc], wr_h, ar);
            az = mfma16(ax[kc], wz_i, az);
            az = mfma16(ah[kc], wz_h, az);
            ai = mfma16(ax[kc], wn_i, ai);
            ag = mfma16(ah[kc], wn_h, ag);
        }
#pragma unroll
        for (int j = 0; j < 4; ++j) {
            const long row = rbase + ko * 4 + j;
            if (row < N) {
                const float r = 1.f / (1.f + __expf(-(ar[j] + br)));
                const float z = 1.f / (1.f + __expf(-(az[j] + bz)));
                const float pre_ = (ai[j] + bi) + r * (ag[j] + bh);
                const float n = 1.f - 2.f / (1.f + __expf(2.f * pre_));
                out[row * 128 + col] = (1.f - z) * n + z * hp[row * 128 + col];
            }
        }
    }
}

// ---------------------------------------------------------------------------
// FUSED gather + GRU v2: edge-balanced gather into LDS hacc (f32 atomics,
// contiguous CSR range for the block's 64 rows -> zero wave divergence),
// then frag conversion + GRU. hacc (33KB) is aliased as the Lw buffer.
// ---------------------------------------------------------------------------
__global__ __launch_bounds__(256) void gg_kernel(
    const bf16* __restrict__ xwb,
    const int* __restrict__ rowptr,          // N+1 entries
    const int* __restrict__ csr_src, const float* __restrict__ csr_norm,
    const int* __restrict__ csr_dst,
    const float* __restrict__ dinv, const float* __restrict__ cbias,
    const float* __restrict__ hp,
    const bf16* __restrict__ wih, const bf16* __restrict__ whh,
    const float* __restrict__ bih, const float* __restrict__ bhh,
    float* __restrict__ out, int N)
{
    __shared__ float hacc[64][132];          // 33KB; 132 = 128+4 pad (2-way reads)
    bf16* LwBuf = (bf16*)&hacc[0][0];        // aliased for GRU phase: [6][16][128]

    const int tid  = threadIdx.x;
    const int lane = tid & 63, w = tid >> 6;
    const int lr   = lane & 15, ko = lane >> 4;
    const long rbase = (long)blockIdx.x * 64;
    const long wrow0 = rbase + w * 16;

    long arow = wrow0 + lr; if (arow > N - 1) arow = N - 1;
    const int lrow = (int)(arow - rbase);    // in [0,64)

    // zero hacc (8448 floats = 256 x 33)
    float* hf = &hacc[0][0];
#pragma unroll
    for (int i = 0; i < 33; ++i) hf[tid + 256 * i] = 0.f;

    // prefetch ah frags + self row (latency overlaps the edge phase)
    bf16x8 ah[4], vd[4];
#pragma unroll
    for (int kc = 0; kc < 4; ++kc) {
        ah[kc] = load_a8(hp + arow * 128 + kc * 32 + ko * 8);
        vd[kc] = *(const bf16x8*)(xwb + (long)arow * 128 + kc * 32 + ko * 8);
    }
    __syncthreads();

    // ---- edge-balanced gather: (edge, 16B-chunk) pairs across all threads ----
    {
        const int estart = rowptr[rbase];
        long rend = rbase + 64; if (rend > N) rend = N;
        const int eend = rowptr[rend];
        const int npair = (eend - estart) << 4;
        for (int pi = tid; pi < npair; pi += 256) {
            const int e = estart + (pi >> 4);
            const int c = pi & 15;
            const int   s  = csr_src[e];
            const float nm = csr_norm[e];
            const int   r  = csr_dst[e] - (int)rbase;
            bf16x8 v = *(const bf16x8*)(xwb + (long)s * 128 + c * 8);
            float* hq = &hacc[r][c * 8];
#pragma unroll
            for (int j = 0; j < 8; ++j) atomicAdd(hq + j, (float)v[j] * nm);
        }
    }
    __syncthreads();

    // ---- frag conversion: ax = leaky(hacc + self*dinv^2 + bias) ----
    bf16x8 ax[4];
    {
        const float di = dinv[arow], sl = di * di;
#pragma unroll
        for (int kc = 0; kc < 4; ++kc) {
            const int c0 = kc * 32 + ko * 8;
#pragma unroll
            for (int j = 0; j < 8; ++j) {
                float t = hacc[lrow][c0 + j] + (float)vd[kc][j] * sl + cbias[c0 + j];
                t = (t >= 0.f) ? t : 0.01f * t;
                ax[kc][j] = (bf16)t;
            }
        }
    }
    // (GRU loop's first __syncthreads() fences hacc reads before Lw overwrite)

    // ---- GRU phase (Lw aliased onto hacc memory) ----
    bf16x8 pre[6];
    auto LDW = [&](int tc) {
#pragma unroll
        for (int i = 0; i < 6; ++i) {
            const int ch  = tid + 256 * i;
            const int g   = ch >> 8, rem = ch & 255;
            const int row = rem >> 4, cc = rem & 15;
            const int scc = cc ^ (row & 7);
            pre[i] = *(const bf16x8*)((g < 3 ? wih : whh)
                + (long)(((g % 3) * 128 + tc * 16 + row) * 128 + scc * 8));
        }
    };
    LDW(0);

    for (int tc = 0; tc < 8; ++tc) {
        __syncthreads();
#pragma unroll
        for (int i = 0; i < 6; ++i) {
            const int ch  = tid + 256 * i;
            const int g   = ch >> 8, rem = ch & 255;
            const int row = rem >> 4, cc = rem & 15;
            *(bf16x8*)(LwBuf + g * 2048 + row * 128 + cc * 8) = pre[i];
        }
        __syncthreads();
        if (tc < 7) LDW(tc + 1);

        const int col = tc * 16 + lr;
        const float br = bih[col]       + bhh[col];
        const float bz = bih[128 + col] + bhh[128 + col];
        const float bi = bih[256 + col];
        const float bh = bhh[256 + col];

        f32x4 ar = {0.f, 0.f, 0.f, 0.f};
        f32x4 az = {0.f, 0.f, 0.f, 0.f};
        f32x4 ai = {0.f, 0.f, 0.f, 0.f};
        f32x4 ag = {0.f, 0.f, 0.f, 0.f};
#pragma unroll
        for (int kc = 0; kc < 4; ++kc) {
            const int cc = (kc * 4 + ko) ^ (lr & 7);
            bf16x8 wr_i = *(const bf16x8*)(LwBuf + 0 * 2048 + lr * 128 + cc * 8);
            bf16x8 wz_i = *(const bf16x8*)(LwBuf + 1 * 2048 + lr * 128 + cc * 8);
            bf16x8 wn_i = *(const bf16x8*)(LwBuf + 2 * 2048 + lr * 128 + cc * 8);
            bf16x8 wr_h = *(const bf16x8*)(LwBuf + 3 * 2048 + lr * 128 + cc * 8);
            bf16x8 wz_h = *(const bf16x8*)(LwBuf + 4 * 2048 + lr * 128 + cc * 8);
            bf16x8 wn_h = *(const bf16x8*)(LwBuf + 5 * 2048 + lr * 128 + cc * 8);
            ar = mfma16(ax[kc], wr_i, ar);
            ar = mfma16(ah[kc], wr_h, ar);
            az = mfma16(ax[kc], wz_i, az);
            az = mfma16(ah[kc], wz_h, az);
            ai = mfma16(ax[kc], wn_i, ai);
            ag = mfma16(ah[kc], wn_h, ag);
        }
#pragma unroll
        for (int j = 0; j < 4; ++j) {
            const long row = wrow0 + ko * 4 + j;
            if (row < N) {
                const float r = 1.f / (1.f + __expf(-(ar[j] + br)));
                const float z = 1.f / (1.f + __expf(-(az[j] + bz)));
                const float pre_ = (ai[j] + bi) + r * (ag[j] + bh);
                const float n = 1.f - 2.f / (1.f + __expf(2.f * pre_));
                out[row * 128 + col] = (1.f - z) * n + z * hp[row * 128 + col];
            }
        }
    }
}

// ---------------------------------------------------------------------------
// CSR build chain (kernel-boundary sync; NO grid.sync -- ~100us each on 8 XCDs)
// ---------------------------------------------------------------------------
__global__ void deg_kernel(const int* __restrict__ dst, int* degi, int E) {
    const int e = blockIdx.x * 256 + threadIdx.x;
    if (e < E) atomicAdd(&degi[dst[e]], 1);
}
__global__ void scan1_kernel(const int* __restrict__ degi, int* __restrict__ inc,
                             int* __restrict__ bsum, float* __restrict__ dinv, int N) {
    __shared__ int s[256];
    const int i = blockIdx.x * 256 + threadIdx.x;
    const int d = (i < N) ? degi[i] : 0;
    if (i < N) dinv[i] = rsqrtf((float)d + 1.0f);   // +1 self loop
    s[threadIdx.x] = d;
    __syncthreads();
#pragma unroll
    for (int off = 1; off < 256; off <<= 1) {
        int t = (threadIdx.x >= off) ? s[threadIdx.x - off] : 0;
        __syncthreads();
        s[threadIdx.x] += t;
        __syncthreads();
    }
    if (i < N) inc[i] = s[threadIdx.x];
    if (threadIdx.x == 255) bsum[blockIdx.x] = s[255];
}
__global__ void scan2_kernel(int* bsum, int nb) {
    __shared__ int s[512];
    __shared__ int carry;
    if (threadIdx.x == 0) carry = 0;
    __syncthreads();
    for (int base = 0; base < nb; base += 512) {
        const int i = base + threadIdx.x;
        s[threadIdx.x] = (i < nb) ? bsum[i] : 0;
        __syncthreads();
#pragma unroll
        for (int off = 1; off < 512; off <<= 1) {
            int t = (threadIdx.x >= off) ? s[threadIdx.x - off] : 0;
            __syncthreads();
            s[threadIdx.x] += t;
            __syncthreads();
        }
        const int c = carry;
        if (i < nb) bsum[i] = s[threadIdx.x] + c;
        __syncthreads();
        if (threadIdx.x == 511) carry = c + s[511];
        __syncthreads();
    }
}
__global__ void scan3_kernel(const int* __restrict__ inc, const int* __restrict__ degi,
                             const int* __restrict__ bsum, int* __restrict__ rowptr,
                             int* __restrict__ rp2, int N) {
    const int i = blockIdx.x * 256 + threadIdx.x;
    if (i >= N) return;
    const int prev = (blockIdx.x > 0) ? bsum[blockIdx.x - 1] : 0;
    const int rp = prev + inc[i] - degi[i];   // exclusive prefix
    rowptr[i] = rp;
    rp2[i]    = rp;
    if (i == N - 1) rowptr[N] = rp + degi[i];  // total edge count sentinel
}
__global__ void fill_kernel(const int* __restrict__ src, const int* __restrict__ dst,
                            int* rp2, const float* __restrict__ dinv,
                            int* __restrict__ csr_src, float* __restrict__ csr_norm,
                            int* __restrict__ csr_dst, int E) {
    const int e = blockIdx.x * 256 + threadIdx.x;
    if (e >= E) return;
    const int s = src[e], d = dst[e];
    const int pos = atomicAdd(&rp2[d], 1);
    csr_src[pos]  = s;
    csr_norm[pos] = dinv[s] * dinv[d];
    csr_dst[pos]  = d;
}

// ---------------------------------------------------------------------------
// Standalone gather (fallback path for small ws / column passes)
// ---------------------------------------------------------------------------
template<typename OT>
__global__ __launch_bounds__(256) void gather_kernel(
    const bf16* __restrict__ xwb,
    const int* __restrict__ rowptr, const int* __restrict__ degi,
    const int* __restrict__ csr_src, const float* __restrict__ csr_norm,
    const float* __restrict__ dinv, const float* __restrict__ bias,
    OT* __restrict__ out, int N, int colbase, int cw, int lg)
{
    const long tid = (long)blockIdx.x * 256 + threadIdx.x;
    const long d = tid >> lg;
    const int  c = (int)(tid & ((1 << lg) - 1));
    if (d >= N) return;

    const int start = rowptr[d];
    const int deg   = degi[d];
    const int h     = deg >> 1;
    const bf16* xb  = xwb + c * 8;

    float acca[8] = {0.f, 0.f, 0.f, 0.f, 0.f, 0.f, 0.f, 0.f};
    float accb[8] = {0.f, 0.f, 0.f, 0.f, 0.f, 0.f, 0.f, 0.f};
    for (int k = 0; k < h; ++k) {
        const int   sa = csr_src[start + k];
        const int   sb = csr_src[start + h + k];
        const float na = csr_norm[start + k];
        const float nb_ = csr_norm[start + h + k];
        bf16x8 va = *(const bf16x8*)(xb + (long)sa * cw);
        bf16x8 vb = *(const bf16x8*)(xb + (long)sb * cw);
#pragma unroll
        for (int j = 0; j < 8; ++j) {
            acca[j] += (float)va[j] * na;
            accb[j] += (float)vb[j] * nb_;
        }
    }
    if (deg & 1) {
        const int   s  = csr_src[start + deg - 1];
        const float nm = csr_norm[start + deg - 1];
        bf16x8 v = *(const bf16x8*)(xb + (long)s * cw);
#pragma unroll
        for (int j = 0; j < 8; ++j) acca[j] += (float)v[j] * nm;
    }

    const float di = dinv[d], sl = di * di;
    bf16x8 vd = *(const bf16x8*)(xb + d * cw);
    const int col = colbase + c * 8;
    float v[8];
#pragma unroll
    for (int j = 0; j < 8; ++j) {
        float t = acca[j] + accb[j] + (float)vd[j] * sl + bias[col + j];
        v[j] = (t >= 0.f) ? t : 0.01f * t;
    }
    if constexpr (std::is_same<OT, bf16>::value) {
        bf16x8 o;
#pragma unroll
        for (int j = 0; j < 8; ++j) o[j] = (bf16)v[j];
        *(bf16x8*)(out + d * 128 + col) = o;
    } else {
        f32x4 o0, o1;
#pragma unroll
        for (int j = 0; j < 4; ++j) { o0[j] = v[j]; o1[j] = v[4 + j]; }
        *(f32x4*)(out + d * 128 + col)     = o0;
        *(f32x4*)(out + d * 128 + col + 4) = o1;
    }
}

// ---------------------------------------------------------------------------
// LP head: 16 lanes per edge, shfl reduce.
// ---------------------------------------------------------------------------
__global__ __launch_bounds__(256) void lp_kernel(
    const float* __restrict__ emb, const int* __restrict__ eli,
    const float* __restrict__ wpost, const float* __restrict__ bpost,
    float* __restrict__ logits, int EL)
{
    const long t = (long)blockIdx.x * 256 + threadIdx.x;
    const long e = t >> 4;
    const int  c = (int)(t & 15);
    if (e >= EL) return;
    const long s = eli[e], d = eli[EL + e];

    f32x4 a0 = *(const f32x4*)(emb + s * 128 + c * 8);
    f32x4 a1 = *(const f32x4*)(emb + s * 128 + c * 8 + 4);
    f32x4 b0 = *(const f32x4*)(emb + d * 128 + c * 8);
    f32x4 b1 = *(const f32x4*)(emb + d * 128 + c * 8 + 4);
    f32x4 w00 = *(const f32x4*)(wpost + c * 8);
    f32x4 w01 = *(const f32x4*)(wpost + c * 8 + 4);
    f32x4 w10 = *(const f32x4*)(wpost + 128 + c * 8);
    f32x4 w11 = *(const f32x4*)(wpost + 128 + c * 8 + 4);

    float acc = 0.f;
#pragma unroll
    for (int i = 0; i < 4; ++i) {
        acc += a0[i] * b0[i] * (w00[i] + w10[i]);
        acc += a1[i] * b1[i] * (w01[i] + w11[i]);
    }
#pragma unroll
    for (int m = 1; m < 16; m <<= 1) acc += __shfl_xor(acc, m);
    if (c == 0) logits[e] = acc + bpost[0] + bpost[1];
}

// ---------------------------------------------------------------------------
extern "C" void kernel_launch(void* const* d_in, const int* in_sizes, int n_in,
                              void* d_out, int out_size, void* d_ws, size_t ws_size,
                              hipStream_t stream) {
    const float* x      = (const float*)d_in[0];
    const int*   ei     = (const int*)d_in[1];   // [2,E]: row0=src, row1=dst
    const int*   eli    = (const int*)d_in[2];
    const float* prev0  = (const float*)d_in[3];
    const float* prev1  = (const float*)d_in[4];
    const float* w_pre1 = (const float*)d_in[5];
    const float* b_pre1 = (const float*)d_in[6];
    const float* w_pre2 = (const float*)d_in[7];
    const float* b_pre2 = (const float*)d_in[8];
    const float* w_c1   = (const float*)d_in[9];
    const float* b_c1   = (const float*)d_in[10];
    const float* w_c2   = (const float*)d_in[11];
    const float* b_c2   = (const float*)d_in[12];
    const float* w_post = (const float*)d_in[13];
    const float* b_post = (const float*)d_in[14];
    const float* g1_wih = (const float*)d_in[15];
    const float* g1_whh = (const float*)d_in[16];
    const float* g1_bih = (const float*)d_in[17];
    const float* g1_bhh = (const float*)d_in[18];
    const float* g2_wih = (const float*)d_in[19];
    const float* g2_whh = (const float*)d_in[20];
    const float* g2_bih = (const float*)d_in[21];
    const float* g2_bhh = (const float*)d_in[22];

    const int N  = in_sizes[0] / 128;
    const int E  = in_sizes[1] / 2;
    const int EL = in_sizes[2] / 2;
    const long NH = (long)N * 128;

    // outputs (f32)
    float* out    = (float*)d_out;
    float* logits = out;
    float* emb0   = out + EL;
    float* emb1   = emb0 + NH;
    float* emb2   = emb1 + NH;

    // bf16 intermediates in currently-dead output slots
    bf16* H1b = (bf16*)emb1;   // [N,256] bf16 == emb1 slot
    bf16* H2b = (bf16*)emb2;   // [N,128] bf16 (first half of emb2 slot)
    bf16* h1b = (bf16*)emb2;   // fallback only

    // ---- workspace layout ----
    char* ws = (char*)d_ws;
    size_t p = 0;
    auto alloc = [&](size_t bytes) { size_t o = p; p = (p + bytes + 255) & ~(size_t)255; return o; };
    float* dinv    = (float*)(ws + alloc((size_t)N * 4));
    int*   degi    = (int*)  (ws + alloc((size_t)N * 4));
    int*   inc     = (int*)  (ws + alloc((size_t)N * 4));
    int*   rowptr  = (int*)  (ws + alloc((size_t)(N + 1) * 4));
    int*   rp2     = (int*)  (ws + alloc((size_t)N * 4));
    int*   bsum    = (int*)  (ws + alloc(4096));
    bf16*  wb      = (bf16*) (ws + alloc((size_t)294912 * 2));
    int*   csr_src = (int*)  (ws + alloc((size_t)E * 4));
    float* csr_nrm = (float*)(ws + alloc((size_t)E * 4));
    int*   csr_dst = (int*)  (ws + alloc((size_t)E * 4));
    const size_t fixed = p;
    bf16*  xwb     = (bf16*)(ws + fixed);

    int cw = 128;
    while (cw > 16 && fixed + (size_t)N * cw * 2 > ws_size) cw >>= 1;
    const int lg = __builtin_ctz(cw >> 3);
    const int passes = 128 / cw;
    const bool fused = (cw == 128);
    const bool big_ws = fused &&
        (ws_size >= fixed + (size_t)N * 128 * 2 + (size_t)N * 128 * 2);
    bf16* h2b = big_ws ? (bf16*)(ws + fixed + (size_t)N * 128 * 2) : nullptr;

    bf16* wb_pre1 = wb;
    bf16* wb_pre2 = wb_pre1 + 32768;
    bf16* wb_c1   = wb_pre2 + 32768;
    bf16* wb_c2   = wb_c1 + 16384;
    bf16* wb_g1i  = wb_c2 + 16384;
    bf16* wb_g1h  = wb_g1i + 49152;
    bf16* wb_g2i  = wb_g1h + 49152;
    bf16* wb_g2h  = wb_g2i + 49152;

    const int gB = 256;
    const dim3 blk(gB);
    const int grid_rows128 = (N + 127) / 128;
    const int grid_gru     = (N + 63) / 64;
    const int grid_E       = (E + gB - 1) / gB;
    const int nb           = (N + 255) / 256;

    cvt8_kernel<<<(294912 + 255) / 256, blk, 0, stream>>>(
        w_pre1, w_pre2, w_c1, w_c2, g1_wih, g1_whh, g2_wih, g2_whh, wb);

    // ---- CSR build ----
    hipMemsetAsync(degi, 0, (size_t)N * 4, stream);
    deg_kernel<<<grid_E, blk, 0, stream>>>(ei + E, degi, E);
    scan1_kernel<<<nb, blk, 0, stream>>>(degi, inc, bsum, dinv, N);
    scan2_kernel<<<1, 512, 0, stream>>>(bsum, nb);
    scan3_kernel<<<nb, blk, 0, stream>>>(inc, degi, bsum, rowptr, rp2, N);
    fill_kernel<<<grid_E, blk, 0, stream>>>(ei, ei + E, rp2, dinv, csr_src, csr_nrm, csr_dst, E);

    // ---- preprocess: x -> H1b (bf16) -> H2b (bf16) ----
    gemm_kernel<128, 256, true, true, float, bf16><<<grid_rows128, blk, 0, stream>>>(x, wb_pre1, b_pre1, H1b, N);
    gemm_kernel<256, 128, true, true, bf16,  bf16><<<grid_rows128, blk, 0, stream>>>(H1b, wb_pre2, b_pre2, H2b, N);

    // GRU1: emb0 = gru(H2b, prev0)
    gru_kernel<bf16><<<grid_gru, blk, 0, stream>>>(H2b, prev0, wb_g1i, wb_g1h, g1_bih, g1_bhh, emb0, N);

    auto run_gemm = [&](const float* hin, const bf16* wp) {
        switch (cw) {
        case 128: gemm_kernel<128, 128, false, false, float, bf16><<<grid_rows128, blk, 0, stream>>>(hin, wp, nullptr, xwb, N); break;
        case 64:  gemm_kernel<128, 64,  false, false, float, bf16><<<grid_rows128, blk, 0, stream>>>(hin, wp, nullptr, xwb, N); break;
        case 32:  gemm_kernel<128, 32,  false, false, float, bf16><<<grid_rows128, blk, 0, stream>>>(hin, wp, nullptr, xwb, N); break;
        default:  gemm_kernel<128, 16,  false, false, float, bf16><<<grid_rows128, blk, 0, stream>>>(hin, wp, nullptr, xwb, N); break;
        }
    };

    if (fused) {
        // conv1 + GRU2 fused: emb0 -> xwb -> (edge-balanced gather + gru) -> emb1
        run_gemm(emb0, wb_c1);
        gg_kernel<<<grid_gru, blk, 0, stream>>>(xwb, rowptr, csr_src, csr_nrm, csr_dst,
                                                dinv, b_c1, prev0,
                                                wb_g1i, wb_g1h, g1_bih, g1_bhh, emb1, N);
        // conv2 + GRU3 fused: emb1 -> xwb -> (edge-balanced gather + gru) -> emb2
        run_gemm(emb1, wb_c2);
        gg_kernel<<<grid_gru, blk, 0, stream>>>(xwb, rowptr, csr_src, csr_nrm, csr_dst,
                                                dinv, b_c2, prev1,
                                                wb_g2i, wb_g2h, g2_bih, g2_bhh, emb2, N);
    } else {
        const int grid_ga = (int)((((long)N << lg) + gB - 1) / gB);
        for (int ps = 0; ps < passes; ++ps) {
            run_gemm(emb0, wb_c1 + (size_t)(ps * cw) * 128);
            gather_kernel<bf16><<<grid_ga, blk, 0, stream>>>(xwb, rowptr, degi, csr_src, csr_nrm,
                                                             dinv, b_c1, h1b, N, ps * cw, cw, lg);
        }
        gru_kernel<bf16><<<grid_gru, blk, 0, stream>>>(h1b, prev0, wb_g1i, wb_g1h, g1_bih, g1_bhh, emb1, N);
        for (int ps = 0; ps < passes; ++ps) {
            run_gemm(emb1, wb_c2 + (size_t)(ps * cw) * 128);
            if (big_ws)
                gather_kernel<bf16><<<grid_ga, blk, 0, stream>>>(xwb, rowptr, degi, csr_src, csr_nrm,
                                                                 dinv, b_c2, h2b, N, ps * cw, cw, lg);
            else
                gather_kernel<float><<<grid_ga, blk, 0, stream>>>(xwb, rowptr, degi, csr_src, csr_nrm,
                                                                  dinv, b_c2, emb2, N, ps * cw, cw, lg);
        }
        if (big_ws)
            gru_kernel<bf16><<<grid_gru, blk, 0, stream>>>(h2b, prev1, wb_g2i, wb_g2h, g2_bih, g2_bhh, emb2, N);
        else
            gru_kernel<float><<<grid_gru, blk, 0, stream>>>(emb2, prev1, wb_g2i, wb_g2h, g2_bih, g2_bhh, emb2, N);
    }

    // LP head (16 lanes/edge)
    lp_kernel<<<(int)(((long)EL * 16 + gB - 1) / gB), blk, 0, stream>>>(emb2, eli, w_post, b_post, logits, EL);
}

// Round 13
// 1286.981 us; speedup vs baseline: 1.0232x; 1.0232x over previous
//
#include <hip/hip_runtime.h>
#include <hip/hip_bf16.h>
#include <type_traits>

// ---------------------------------------------------------------------------
// ROLAND GNN forward. Buffers f32; matmuls bf16-MFMA, f32 accum.
// Outputs (concat, f32): logits[EL], emb0[N,128], emb1[N,128], emb2[N,128]
// Round 13: gg reverted to register-accum gather (r12's LDS-atomic gather hit
// a CAS-loop path: 519us). Divergence attacked via degree-sorted row
// permutation (counting sort, 3 tiny kernels) -- each wave's 16 rows have
// ~equal degree, so the per-lane edge loop wastes ~1.1x instead of ~2.1x.
// ---------------------------------------------------------------------------

typedef __bf16 bf16;
typedef __bf16 bf16x8 __attribute__((ext_vector_type(8)));
typedef float  f32x4  __attribute__((ext_vector_type(4)));

#define DEV __device__ __forceinline__

DEV f32x4 mfma16(bf16x8 a, bf16x8 b, f32x4 c) {
    return __builtin_amdgcn_mfma_f32_16x16x32_bf16(a, b, c, 0, 0, 0);
}

DEV bf16x8 load_a8(const float* p) {
    f32x4 lo = *(const f32x4*)p;
    f32x4 hi = *(const f32x4*)(p + 4);
    bf16x8 v;
    v[0] = (bf16)lo[0]; v[1] = (bf16)lo[1]; v[2] = (bf16)lo[2]; v[3] = (bf16)lo[3];
    v[4] = (bf16)hi[0]; v[5] = (bf16)hi[1]; v[6] = (bf16)hi[2]; v[7] = (bf16)hi[3];
    return v;
}
DEV bf16x8 load_a8(const bf16* p) { return *(const bf16x8*)p; }

// single fused f32->bf16 conversion of all 8 weight matrices into wb
__global__ void cvt8_kernel(const float* s0, const float* s1, const float* s2, const float* s3,
                            const float* s4, const float* s5, const float* s6, const float* s7,
                            bf16* __restrict__ wb) {
    const int i = blockIdx.x * 256 + threadIdx.x;
    if (i >= 294912) return;
    float v;
    if      (i < 32768)  v = s0[i];
    else if (i < 65536)  v = s1[i - 32768];
    else if (i < 81920)  v = s2[i - 65536];
    else if (i < 98304)  v = s3[i - 81920];
    else if (i < 147456) v = s4[i - 98304];
    else if (i < 196608) v = s5[i - 147456];
    else if (i < 245760) v = s6[i - 196608];
    else                 v = s7[i - 245760];
    wb[i] = (bf16)v;
}

// ---------------------------------------------------------------------------
// GEMM: C[M,Co] = act(A[M,Ci] @ W[Co,Ci]^T + bias). 2 M-tiles/wave.
// ---------------------------------------------------------------------------
template<int Ci, int Co, bool ACT, bool BIAS, typename AT, typename OT>
__global__ __launch_bounds__(256) void gemm_kernel(
    const AT* __restrict__ A, const bf16* __restrict__ W,
    const float* __restrict__ bias, OT* __restrict__ C, int M)
{
    const int tid  = threadIdx.x;
    const int lane = tid & 63, w = tid >> 6;
    const int lr   = lane & 15, ko = lane >> 4;
    const int rbase = blockIdx.x * 128 + w * 32;

    constexpr int KC = Ci / 32;
    constexpr int NT = Co / 16;

    bf16x8 a[2][KC];
#pragma unroll
    for (int m = 0; m < 2; ++m) {
        long arow = rbase + m * 16 + lr; if (arow > M - 1) arow = M - 1;  // clamped rows never stored
#pragma unroll
        for (int kc = 0; kc < KC; ++kc)
            a[m][kc] = load_a8(A + arow * Ci + kc * 32 + ko * 8);
    }

#pragma unroll
    for (int t = 0; t < NT; ++t) {
        f32x4 acc0 = {0.f, 0.f, 0.f, 0.f};
        f32x4 acc1 = {0.f, 0.f, 0.f, 0.f};
        const bf16* wp = W + (long)(t * 16 + lr) * Ci + ko * 8;
#pragma unroll
        for (int kc = 0; kc < KC; ++kc) {
            bf16x8 wf = *(const bf16x8*)(wp + kc * 32);
            acc0 = mfma16(a[0][kc], wf, acc0);
            acc1 = mfma16(a[1][kc], wf, acc1);
        }

        const int col = t * 16 + lr;
        float bv = 0.f;
        if (BIAS) bv = bias[col];
#pragma unroll
        for (int j = 0; j < 4; ++j) {
            const int r0 = rbase + ko * 4 + j;
            if (r0 < M) {
                float v = acc0[j] + bv;
                if (ACT) v = (v >= 0.f) ? v : 0.01f * v;
                C[(long)r0 * Co + col] = (OT)v;
            }
            const int r1 = rbase + 16 + ko * 4 + j;
            if (r1 < M) {
                float v = acc1[j] + bv;
                if (ACT) v = (v >= 0.f) ? v : 0.01f * v;
                C[(long)r1 * Co + col] = (OT)v;
            }
        }
    }
}

// ---------------------------------------------------------------------------
// GRUCell, 64-row blocks (4 waves x 16 rows), LDS weight tiles + reg prefetch.
// Safe for out == x (f32 path): all A-frag reads precede the first barrier.
// ---------------------------------------------------------------------------
template<typename XT>
__global__ __launch_bounds__(256) void gru_kernel(
    const XT* x, const float* __restrict__ hp,
    const bf16* __restrict__ wih, const bf16* __restrict__ whh,
    const float* __restrict__ bih, const float* __restrict__ bhh,
    float* out, int N)
{
    __shared__ bf16 Lw[6][16][128];   // 24 KB

    const int tid  = threadIdx.x;
    const int lane = tid & 63, w = tid >> 6;
    const int lr   = lane & 15, ko = lane >> 4;
    const long rbase = (long)blockIdx.x * 64 + w * 16;

    long arow = rbase + lr; if (arow > N - 1) arow = N - 1;
    bf16x8 ax[4], ah[4];
#pragma unroll
    for (int kc = 0; kc < 4; ++kc) {
        ax[kc] = load_a8(x  + arow * 128 + kc * 32 + ko * 8);
        ah[kc] = load_a8(hp + arow * 128 + kc * 32 + ko * 8);
    }

    bf16x8 pre[6];
    auto LDW = [&](int tc) {
#pragma unroll
        for (int i = 0; i < 6; ++i) {
            const int ch  = tid + 256 * i;
            const int g   = ch >> 8, rem = ch & 255;
            const int row = rem >> 4, cc = rem & 15;
            const int scc = cc ^ (row & 7);
            pre[i] = *(const bf16x8*)((g < 3 ? wih : whh)
                + (long)(((g % 3) * 128 + tc * 16 + row) * 128 + scc * 8));
        }
    };
    LDW(0);

    for (int tc = 0; tc < 8; ++tc) {
        __syncthreads();
#pragma unroll
        for (int i = 0; i < 6; ++i) {
            const int ch  = tid + 256 * i;
            const int g   = ch >> 8, rem = ch & 255;
            const int row = rem >> 4, cc = rem & 15;
            *(bf16x8*)(&Lw[g][row][cc * 8]) = pre[i];
        }
        __syncthreads();
        if (tc < 7) LDW(tc + 1);

        const int col = tc * 16 + lr;
        const float br = bih[col]       + bhh[col];
        const float bz = bih[128 + col] + bhh[128 + col];
        const float bi = bih[256 + col];
        const float bh = bhh[256 + col];

        f32x4 ar = {0.f, 0.f, 0.f, 0.f};
        f32x4 az = {0.f, 0.f, 0.f, 0.f};
        f32x4 ai = {0.f, 0.f, 0.f, 0.f};
        f32x4 ag = {0.f, 0.f, 0.f, 0.f};
#pragma unroll
        for (int kc = 0; kc < 4; ++kc) {
            const int cc = (kc * 4 + ko) ^ (lr & 7);
            bf16x8 wr_i = *(const bf16x8*)(&Lw[0][lr][cc * 8]);
            bf16x8 wz_i = *(const bf16x8*)(&Lw[1][lr][cc * 8]);
            bf16x8 wn_i = *(const bf16x8*)(&Lw[2][lr][cc * 8]);
            bf16x8 wr_h = *(const bf16x8*)(&Lw[3][lr][cc * 8]);
            bf16x8 wz_h = *(const bf16x8*)(&Lw[4][lr][cc * 8]);
            bf16x8 wn_h = *(const bf16x8*)(&Lw[5][lr][cc * 8]);
            ar = mfma16(ax[kc], wr_i, ar);
            ar = mfma16(ah[kc], wr_h, ar);
            az = mfma16(ax[kc], wz_i, az);
            az = mfma16(ah[kc], wz_h, az);
            ai = mfma16(ax[kc], wn_i, ai);
            ag = mfma16(ah[kc], wn_h, ag);
        }
#pragma unroll
        for (int j = 0; j < 4; ++j) {
            const long row = rbase + ko * 4 + j;
            if (row < N) {
                const float r = 1.f / (1.f + __expf(-(ar[j] + br)));
                const float z = 1.f / (1.f + __expf(-(az[j] + bz)));
                const float pre_ = (ai[j] + bi) + r * (ag[j] + bh);
                const float n = 1.f - 2.f / (1.f + __expf(2.f * pre_));
                out[row * 128 + col] = (1.f - z) * n + z * hp[row * 128 + col];
            }
        }
    }
}

// ---------------------------------------------------------------------------
// FUSED gather + GRU (register-accum gather, round-11 proven) with
// degree-sorted row permutation: lane's row = perm[block row] so each wave's
// 16 rows have ~equal degree (minimal exec-mask waste in the edge loop).
// perm is a bijection -> writes race-free (guarded by original index < N).
// ---------------------------------------------------------------------------
__global__ __launch_bounds__(256) void gg_kernel(
    const bf16* __restrict__ xwb,
    const int* __restrict__ rowptr, const int* __restrict__ degi,
    const int* __restrict__ csr_src, const float* __restrict__ csr_norm,
    const int* __restrict__ perm,
    const float* __restrict__ dinv, const float* __restrict__ cbias,
    const float* __restrict__ hp,
    const bf16* __restrict__ wih, const bf16* __restrict__ whh,
    const float* __restrict__ bih, const float* __restrict__ bhh,
    float* __restrict__ out, int N)
{
    __shared__ bf16 Lw[6][16][128];   // 24 KB
    __shared__ int  sperm[64];

    const int tid  = threadIdx.x;
    const int lane = tid & 63, w = tid >> 6;
    const int lr   = lane & 15, ko = lane >> 4;
    const long rbase = (long)blockIdx.x * 64;
    const long wrow0 = rbase + w * 16;

    if (tid < 64) {
        long ii = rbase + tid; if (ii > N - 1) ii = N - 1;
        sperm[tid] = perm[ii];
    }
    __syncthreads();

    const long arow = sperm[w * 16 + lr];   // this lane's gather/compute row

    // ---- gather phase: h[arow, ko*8 + kc*32 .. +8) in f32 registers ----
    float acc[4][8];
#pragma unroll
    for (int kc = 0; kc < 4; ++kc)
#pragma unroll
        for (int j = 0; j < 8; ++j) acc[kc][j] = 0.f;
    {
        const int start = rowptr[arow];
        const int deg   = degi[arow];
        const bf16* xb  = xwb + ko * 8;
        for (int k = 0; k < deg; ++k) {
            const int   s  = csr_src[start + k];
            const float nm = csr_norm[start + k];
            const bf16* vp = xb + (long)s * 128;
            bf16x8 v0 = *(const bf16x8*)(vp);
            bf16x8 v1 = *(const bf16x8*)(vp + 32);
            bf16x8 v2 = *(const bf16x8*)(vp + 64);
            bf16x8 v3 = *(const bf16x8*)(vp + 96);
#pragma unroll
            for (int j = 0; j < 8; ++j) {
                acc[0][j] += (float)v0[j] * nm;
                acc[1][j] += (float)v1[j] * nm;
                acc[2][j] += (float)v2[j] * nm;
                acc[3][j] += (float)v3[j] * nm;
            }
        }
    }

    bf16x8 ax[4], ah[4];
    {
        const float di = dinv[arow], sl = di * di;
        const bf16* vp = xwb + (long)arow * 128 + ko * 8;
#pragma unroll
        for (int kc = 0; kc < 4; ++kc) {
            bf16x8 vd = *(const bf16x8*)(vp + kc * 32);
#pragma unroll
            for (int j = 0; j < 8; ++j) {
                float t = acc[kc][j] + (float)vd[j] * sl + cbias[kc * 32 + ko * 8 + j];
                t = (t >= 0.f) ? t : 0.01f * t;
                ax[kc][j] = (bf16)t;
            }
            ah[kc] = load_a8(hp + arow * 128 + kc * 32 + ko * 8);
        }
    }

    // ---- GRU phase ----
    bf16x8 pre[6];
    auto LDW = [&](int tc) {
#pragma unroll
        for (int i = 0; i < 6; ++i) {
            const int ch  = tid + 256 * i;
            const int g   = ch >> 8, rem = ch & 255;
            const int row = rem >> 4, cc = rem & 15;
            const int scc = cc ^ (row & 7);
            pre[i] = *(const bf16x8*)((g < 3 ? wih : whh)
                + (long)(((g % 3) * 128 + tc * 16 + row) * 128 + scc * 8));
        }
    };
    LDW(0);

    for (int tc = 0; tc < 8; ++tc) {
        __syncthreads();
#pragma unroll
        for (int i = 0; i < 6; ++i) {
            const int ch  = tid + 256 * i;
            const int g   = ch >> 8, rem = ch & 255;
            const int row = rem >> 4, cc = rem & 15;
            *(bf16x8*)(&Lw[g][row][cc * 8]) = pre[i];
        }
        __syncthreads();
        if (tc < 7) LDW(tc + 1);

        const int col = tc * 16 + lr;
        const float br = bih[col]       + bhh[col];
        const float bz = bih[128 + col] + bhh[128 + col];
        const float bi = bih[256 + col];
        const float bh = bhh[256 + col];

        f32x4 ar = {0.f, 0.f, 0.f, 0.f};
        f32x4 az = {0.f, 0.f, 0.f, 0.f};
        f32x4 ai = {0.f, 0.f, 0.f, 0.f};
        f32x4 ag = {0.f, 0.f, 0.f, 0.f};
#pragma unroll
        for (int kc = 0; kc < 4; ++kc) {
            const int cc = (kc * 4 + ko) ^ (lr & 7);
            bf16x8 wr_i = *(const bf16x8*)(&Lw[0][lr][cc * 8]);
            bf16x8 wz_i = *(const bf16x8*)(&Lw[1][lr][cc * 8]);
            bf16x8 wn_i = *(const bf16x8*)(&Lw[2][lr][cc * 8]);
            bf16x8 wr_h = *(const bf16x8*)(&Lw[3][lr][cc * 8]);
            bf16x8 wz_h = *(const bf16x8*)(&Lw[4][lr][cc * 8]);
            bf16x8 wn_h = *(const bf16x8*)(&Lw[5][lr][cc * 8]);
            ar = mfma16(ax[kc], wr_i, ar);
            ar = mfma16(ah[kc], wr_h, ar);
            az = mfma16(ax[kc], wz_i, az);
            az = mfma16(ah[kc], wz_h, az);
            ai = mfma16(ax[kc], wn_i, ai);
            ag = mfma16(ah[kc], wn_h, ag);
        }
#pragma unroll
        for (int j = 0; j < 4; ++j) {
            if (wrow0 + ko * 4 + j < N) {
                const long row = sperm[w * 16 + ko * 4 + j];
                const float r = 1.f / (1.f + __expf(-(ar[j] + br)));
                const float z = 1.f / (1.f + __expf(-(az[j] + bz)));
                const float pre_ = (ai[j] + bi) + r * (ag[j] + bh);
                const float n = 1.f - 2.f / (1.f + __expf(2.f * pre_));
                out[row * 128 + col] = (1.f - z) * n + z * hp[row * 128 + col];
            }
        }
    }
}

// ---------------------------------------------------------------------------
// CSR build chain (kernel-boundary sync; NO grid.sync -- ~100us each on 8 XCDs)
// ---------------------------------------------------------------------------
__global__ void deg_kernel(const int* __restrict__ dst, int* degi, int E) {
    const int e = blockIdx.x * 256 + threadIdx.x;
    if (e < E) atomicAdd(&degi[dst[e]], 1);
}
__global__ void scan1_kernel(const int* __restrict__ degi, int* __restrict__ inc,
                             int* __restrict__ bsum, float* __restrict__ dinv, int N) {
    __shared__ int s[256];
    const int i = blockIdx.x * 256 + threadIdx.x;
    const int d = (i < N) ? degi[i] : 0;
    if (i < N) dinv[i] = rsqrtf((float)d + 1.0f);   // +1 self loop
    s[threadIdx.x] = d;
    __syncthreads();
#pragma unroll
    for (int off = 1; off < 256; off <<= 1) {
        int t = (threadIdx.x >= off) ? s[threadIdx.x - off] : 0;
        __syncthreads();
        s[threadIdx.x] += t;
        __syncthreads();
    }
    if (i < N) inc[i] = s[threadIdx.x];
    if (threadIdx.x == 255) bsum[blockIdx.x] = s[255];
}
__global__ void scan2_kernel(int* bsum, int nb) {
    __shared__ int s[512];
    __shared__ int carry;
    if (threadIdx.x == 0) carry = 0;
    __syncthreads();
    for (int base = 0; base < nb; base += 512) {
        const int i = base + threadIdx.x;
        s[threadIdx.x] = (i < nb) ? bsum[i] : 0;
        __syncthreads();
#pragma unroll
        for (int off = 1; off < 512; off <<= 1) {
            int t = (threadIdx.x >= off) ? s[threadIdx.x - off] : 0;
            __syncthreads();
            s[threadIdx.x] += t;
            __syncthreads();
        }
        const int c = carry;
        if (i < nb) bsum[i] = s[threadIdx.x] + c;
        __syncthreads();
        if (threadIdx.x == 511) carry = c + s[511];
        __syncthreads();
    }
}
__global__ void scan3_kernel(const int* __restrict__ inc, const int* __restrict__ degi,
                             const int* __restrict__ bsum, int* __restrict__ rowptr,
                             int* __restrict__ rp2, int N) {
    const int i = blockIdx.x * 256 + threadIdx.x;
    if (i >= N) return;
    const int prev = (blockIdx.x > 0) ? bsum[blockIdx.x - 1] : 0;
    const int rp = prev + inc[i] - degi[i];   // exclusive prefix
    rowptr[i] = rp;
    rp2[i]    = rp;
    if (i == N - 1) rowptr[N] = rp + degi[i];
}
__global__ void fill_kernel(const int* __restrict__ src, const int* __restrict__ dst,
                            int* rp2, const float* __restrict__ dinv,
                            int* __restrict__ csr_src, float* __restrict__ csr_norm, int E) {
    const int e = blockIdx.x * 256 + threadIdx.x;
    if (e >= E) return;
    const int s = src[e], d = dst[e];
    const int pos = atomicAdd(&rp2[d], 1);
    csr_src[pos]  = s;
    csr_norm[pos] = dinv[s] * dinv[d];
}

// ---- degree counting sort: 64-bin hist -> exclusive scan -> scatter ----
__global__ void dhist_kernel(const int* __restrict__ degi, int* dhist, int N) {
    const int i = blockIdx.x * 256 + threadIdx.x;
    if (i < N) {
        int b = degi[i]; if (b > 63) b = 63;
        atomicAdd(&dhist[b], 1);
    }
}
__global__ void dscan_kernel(int* dhist) {   // 1 block, 64 threads
    __shared__ int s[64];
    const int t = threadIdx.x;
    const int orig = dhist[t];
    s[t] = orig;
    __syncthreads();
#pragma unroll
    for (int off = 1; off < 64; off <<= 1) {
        int v = (t >= off) ? s[t - off] : 0;
        __syncthreads();
        s[t] += v;
        __syncthreads();
    }
    dhist[t] = s[t] - orig;   // exclusive prefix
}
__global__ void dscatter_kernel(const int* __restrict__ degi, int* dhist,
                                int* __restrict__ perm, int N) {
    const int i = blockIdx.x * 256 + threadIdx.x;
    if (i < N) {
        int b = degi[i]; if (b > 63) b = 63;
        const int pos = atomicAdd(&dhist[b], 1);
        perm[pos] = i;
    }
}

// ---------------------------------------------------------------------------
// Standalone gather (fallback path for small ws / column passes)
// ---------------------------------------------------------------------------
template<typename OT>
__global__ __launch_bounds__(256) void gather_kernel(
    const bf16* __restrict__ xwb,
    const int* __restrict__ rowptr, const int* __restrict__ degi,
    const int* __restrict__ csr_src, const float* __restrict__ csr_norm,
    const float* __restrict__ dinv, const float* __restrict__ bias,
    OT* __restrict__ out, int N, int colbase, int cw, int lg)
{
    const long tid = (long)blockIdx.x * 256 + threadIdx.x;
    const long d = tid >> lg;
    const int  c = (int)(tid & ((1 << lg) - 1));
    if (d >= N) return;

    const int start = rowptr[d];
    const int deg   = degi[d];
    const int h     = deg >> 1;
    const bf16* xb  = xwb + c * 8;

    float acca[8] = {0.f, 0.f, 0.f, 0.f, 0.f, 0.f, 0.f, 0.f};
    float accb[8] = {0.f, 0.f, 0.f, 0.f, 0.f, 0.f, 0.f, 0.f};
    for (int k = 0; k < h; ++k) {
        const int   sa = csr_src[start + k];
        const int   sb = csr_src[start + h + k];
        const float na = csr_norm[start + k];
        const float nb_ = csr_norm[start + h + k];
        bf16x8 va = *(const bf16x8*)(xb + (long)sa * cw);
        bf16x8 vb = *(const bf16x8*)(xb + (long)sb * cw);
#pragma unroll
        for (int j = 0; j < 8; ++j) {
            acca[j] += (float)va[j] * na;
            accb[j] += (float)vb[j] * nb_;
        }
    }
    if (deg & 1) {
        const int   s  = csr_src[start + deg - 1];
        const float nm = csr_norm[start + deg - 1];
        bf16x8 v = *(const bf16x8*)(xb + (long)s * cw);
#pragma unroll
        for (int j = 0; j < 8; ++j) acca[j] += (float)v[j] * nm;
    }

    const float di = dinv[d], sl = di * di;
    bf16x8 vd = *(const bf16x8*)(xb + d * cw);
    const int col = colbase + c * 8;
    float v[8];
#pragma unroll
    for (int j = 0; j < 8; ++j) {
        float t = acca[j] + accb[j] + (float)vd[j] * sl + bias[col + j];
        v[j] = (t >= 0.f) ? t : 0.01f * t;
    }
    if constexpr (std::is_same<OT, bf16>::value) {
        bf16x8 o;
#pragma unroll
        for (int j = 0; j < 8; ++j) o[j] = (bf16)v[j];
        *(bf16x8*)(out + d * 128 + col) = o;
    } else {
        f32x4 o0, o1;
#pragma unroll
        for (int j = 0; j < 4; ++j) { o0[j] = v[j]; o1[j] = v[4 + j]; }
        *(f32x4*)(out + d * 128 + col)     = o0;
        *(f32x4*)(out + d * 128 + col + 4) = o1;
    }
}

// ---------------------------------------------------------------------------
// LP head: 16 lanes per edge, shfl reduce.
// ---------------------------------------------------------------------------
__global__ __launch_bounds__(256) void lp_kernel(
    const float* __restrict__ emb, const int* __restrict__ eli,
    const float* __restrict__ wpost, const float* __restrict__ bpost,
    float* __restrict__ logits, int EL)
{
    const long t = (long)blockIdx.x * 256 + threadIdx.x;
    const long e = t >> 4;
    const int  c = (int)(t & 15);
    if (e >= EL) return;
    const long s = eli[e], d = eli[EL + e];

    f32x4 a0 = *(const f32x4*)(emb + s * 128 + c * 8);
    f32x4 a1 = *(const f32x4*)(emb + s * 128 + c * 8 + 4);
    f32x4 b0 = *(const f32x4*)(emb + d * 128 + c * 8);
    f32x4 b1 = *(const f32x4*)(emb + d * 128 + c * 8 + 4);
    f32x4 w00 = *(const f32x4*)(wpost + c * 8);
    f32x4 w01 = *(const f32x4*)(wpost + c * 8 + 4);
    f32x4 w10 = *(const f32x4*)(wpost + 128 + c * 8);
    f32x4 w11 = *(const f32x4*)(wpost + 128 + c * 8 + 4);

    float acc = 0.f;
#pragma unroll
    for (int i = 0; i < 4; ++i) {
        acc += a0[i] * b0[i] * (w00[i] + w10[i]);
        acc += a1[i] * b1[i] * (w01[i] + w11[i]);
    }
#pragma unroll
    for (int m = 1; m < 16; m <<= 1) acc += __shfl_xor(acc, m);
    if (c == 0) logits[e] = acc + bpost[0] + bpost[1];
}

// ---------------------------------------------------------------------------
extern "C" void kernel_launch(void* const* d_in, const int* in_sizes, int n_in,
                              void* d_out, int out_size, void* d_ws, size_t ws_size,
                              hipStream_t stream) {
    const float* x      = (const float*)d_in[0];
    const int*   ei     = (const int*)d_in[1];   // [2,E]: row0=src, row1=dst
    const int*   eli    = (const int*)d_in[2];
    const float* prev0  = (const float*)d_in[3];
    const float* prev1  = (const float*)d_in[4];
    const float* w_pre1 = (const float*)d_in[5];
    const float* b_pre1 = (const float*)d_in[6];
    const float* w_pre2 = (const float*)d_in[7];
    const float* b_pre2 = (const float*)d_in[8];
    const float* w_c1   = (const float*)d_in[9];
    const float* b_c1   = (const float*)d_in[10];
    const float* w_c2   = (const float*)d_in[11];
    const float* b_c2   = (const float*)d_in[12];
    const float* w_post = (const float*)d_in[13];
    const float* b_post = (const float*)d_in[14];
    const float* g1_wih = (const float*)d_in[15];
    const float* g1_whh = (const float*)d_in[16];
    const float* g1_bih = (const float*)d_in[17];
    const float* g1_bhh = (const float*)d_in[18];
    const float* g2_wih = (const float*)d_in[19];
    const float* g2_whh = (const float*)d_in[20];
    const float* g2_bih = (const float*)d_in[21];
    const float* g2_bhh = (const float*)d_in[22];

    const int N  = in_sizes[0] / 128;
    const int E  = in_sizes[1] / 2;
    const int EL = in_sizes[2] / 2;
    const long NH = (long)N * 128;

    // outputs (f32)
    float* out    = (float*)d_out;
    float* logits = out;
    float* emb0   = out + EL;
    float* emb1   = emb0 + NH;
    float* emb2   = emb1 + NH;

    // bf16 intermediates in currently-dead output slots
    bf16* H1b = (bf16*)emb1;   // [N,256] bf16 == emb1 slot
    bf16* H2b = (bf16*)emb2;   // [N,128] bf16 (first half of emb2 slot)
    bf16* h1b = (bf16*)emb2;   // fallback only

    // ---- workspace layout ----
    char* ws = (char*)d_ws;
    size_t p = 0;
    auto alloc = [&](size_t bytes) { size_t o = p; p = (p + bytes + 255) & ~(size_t)255; return o; };
    float* dinv    = (float*)(ws + alloc((size_t)N * 4));
    int*   degi    = (int*)  (ws + alloc((size_t)N * 4));
    int*   inc     = (int*)  (ws + alloc((size_t)N * 4));
    int*   rowptr  = (int*)  (ws + alloc((size_t)(N + 1) * 4));
    int*   rp2     = (int*)  (ws + alloc((size_t)N * 4));
    int*   perm    = (int*)  (ws + alloc((size_t)N * 4));
    int*   bsum    = (int*)  (ws + alloc(4096));
    int*   dhist   = (int*)  (ws + alloc(256));
    bf16*  wb      = (bf16*) (ws + alloc((size_t)294912 * 2));
    int*   csr_src = (int*)  (ws + alloc((size_t)E * 4));
    float* csr_nrm = (float*)(ws + alloc((size_t)E * 4));
    const size_t fixed = p;
    bf16*  xwb     = (bf16*)(ws + fixed);

    int cw = 128;
    while (cw > 16 && fixed + (size_t)N * cw * 2 > ws_size) cw >>= 1;
    const int lg = __builtin_ctz(cw >> 3);
    const int passes = 128 / cw;
    const bool fused = (cw == 128);
    const bool big_ws = fused &&
        (ws_size >= fixed + (size_t)N * 128 * 2 + (size_t)N * 128 * 2);
    bf16* h2b = big_ws ? (bf16*)(ws + fixed + (size_t)N * 128 * 2) : nullptr;

    bf16* wb_pre1 = wb;
    bf16* wb_pre2 = wb_pre1 + 32768;
    bf16* wb_c1   = wb_pre2 + 32768;
    bf16* wb_c2   = wb_c1 + 16384;
    bf16* wb_g1i  = wb_c2 + 16384;
    bf16* wb_g1h  = wb_g1i + 49152;
    bf16* wb_g2i  = wb_g1h + 49152;
    bf16* wb_g2h  = wb_g2i + 49152;

    const int gB = 256;
    const dim3 blk(gB);
    const int grid_rows128 = (N + 127) / 128;
    const int grid_gru     = (N + 63) / 64;
    const int grid_E       = (E + gB - 1) / gB;
    const int grid_N       = (N + gB - 1) / gB;
    const int nb           = (N + 255) / 256;

    cvt8_kernel<<<(294912 + 255) / 256, blk, 0, stream>>>(
        w_pre1, w_pre2, w_c1, w_c2, g1_wih, g1_whh, g2_wih, g2_whh, wb);

    // ---- CSR build + degree sort ----
    hipMemsetAsync(degi, 0, (size_t)N * 4, stream);
    deg_kernel<<<grid_E, blk, 0, stream>>>(ei + E, degi, E);
    scan1_kernel<<<nb, blk, 0, stream>>>(degi, inc, bsum, dinv, N);
    scan2_kernel<<<1, 512, 0, stream>>>(bsum, nb);
    scan3_kernel<<<nb, blk, 0, stream>>>(inc, degi, bsum, rowptr, rp2, N);
    fill_kernel<<<grid_E, blk, 0, stream>>>(ei, ei + E, rp2, dinv, csr_src, csr_nrm, E);
    hipMemsetAsync(dhist, 0, 256, stream);
    dhist_kernel<<<grid_N, blk, 0, stream>>>(degi, dhist, N);
    dscan_kernel<<<1, 64, 0, stream>>>(dhist);
    dscatter_kernel<<<grid_N, blk, 0, stream>>>(degi, dhist, perm, N);

    // ---- preprocess: x -> H1b (bf16) -> H2b (bf16) ----
    gemm_kernel<128, 256, true, true, float, bf16><<<grid_rows128, blk, 0, stream>>>(x, wb_pre1, b_pre1, H1b, N);
    gemm_kernel<256, 128, true, true, bf16,  bf16><<<grid_rows128, blk, 0, stream>>>(H1b, wb_pre2, b_pre2, H2b, N);

    // GRU1: emb0 = gru(H2b, prev0)
    gru_kernel<bf16><<<grid_gru, blk, 0, stream>>>(H2b, prev0, wb_g1i, wb_g1h, g1_bih, g1_bhh, emb0, N);

    auto run_gemm = [&](const float* hin, const bf16* wp) {
        switch (cw) {
        case 128: gemm_kernel<128, 128, false, false, float, bf16><<<grid_rows128, blk, 0, stream>>>(hin, wp, nullptr, xwb, N); break;
        case 64:  gemm_kernel<128, 64,  false, false, float, bf16><<<grid_rows128, blk, 0, stream>>>(hin, wp, nullptr, xwb, N); break;
        case 32:  gemm_kernel<128, 32,  false, false, float, bf16><<<grid_rows128, blk, 0, stream>>>(hin, wp, nullptr, xwb, N); break;
        default:  gemm_kernel<128, 16,  false, false, float, bf16><<<grid_rows128, blk, 0, stream>>>(hin, wp, nullptr, xwb, N); break;
        }
    };

    if (fused) {
        // conv1 + GRU2 fused: emb0 -> xwb -> (gather+gru, degree-sorted) -> emb1
        run_gemm(emb0, wb_c1);
        gg_kernel<<<grid_gru, blk, 0, stream>>>(xwb, rowptr, degi, csr_src, csr_nrm, perm,
                                                dinv, b_c1, prev0,
                                                wb_g1i, wb_g1h, g1_bih, g1_bhh, emb1, N);
        // conv2 + GRU3 fused: emb1 -> xwb -> (gather+gru, degree-sorted) -> emb2
        run_gemm(emb1, wb_c2);
        gg_kernel<<<grid_gru, blk, 0, stream>>>(xwb, rowptr, degi, csr_src, csr_nrm, perm,
                                                dinv, b_c2, prev1,
                                                wb_g2i, wb_g2h, g2_bih, g2_bhh, emb2, N);
    } else {
        const int grid_ga = (int)((((long)N << lg) + gB - 1) / gB);
        for (int ps = 0; ps < passes; ++ps) {
            run_gemm(emb0, wb_c1 + (size_t)(ps * cw) * 128);
            gather_kernel<bf16><<<grid_ga, blk, 0, stream>>>(xwb, rowptr, degi, csr_src, csr_nrm,
                                                             dinv, b_c1, h1b, N, ps * cw, cw, lg);
        }
        gru_kernel<bf16><<<grid_gru, blk, 0, stream>>>(h1b, prev0, wb_g1i, wb_g1h, g1_bih, g1_bhh, emb1, N);
        for (int ps = 0; ps < passes; ++ps) {
            run_gemm(emb1, wb_c2 + (size_t)(ps * cw) * 128);
            if (big_ws)
                gather_kernel<bf16><<<grid_ga, blk, 0, stream>>>(xwb, rowptr, degi, csr_src, csr_nrm,
                                                                 dinv, b_c2, h2b, N, ps * cw, cw, lg);
            else
                gather_kernel<float><<<grid_ga, blk, 0, stream>>>(xwb, rowptr, degi, csr_src, csr_nrm,
                                                                  dinv, b_c2, emb2, N, ps * cw, cw, lg);
        }
        if (big_ws)
            gru_kernel<bf16><<<grid_gru, blk, 0, stream>>>(h2b, prev1, wb_g2i, wb_g2h, g2_bih, g2_bhh, emb2, N);
        else
            gru_kernel<float><<<grid_gru, blk, 0, stream>>>(emb2, prev1, wb_g2i, wb_g2h, g2_bih, g2_bhh, emb2, N);
    }

    // LP head (16 lanes/edge)
    lp_kernel<<<(int)(((long)EL * 16 + gB - 1) / gB), blk, 0, stream>>>(emb2, eli, w_post, b_post, logits, EL);
}

// Round 14
// 536.938 us; speedup vs baseline: 2.4525x; 2.3969x over previous
//
#include <hip/hip_runtime.h>
#include <hip/hip_bf16.h>
#include <type_traits>

// ---------------------------------------------------------------------------
// ROLAND GNN forward. Buffers f32; matmuls bf16-MFMA, f32 accum.
// Outputs (concat, f32): logits[EL], emb0[N,128], emb1[N,128], emb2[N,128]
// Round 14: exact round-11 structure (proven 534us). r12 (LDS-atomic gather:
// CAS-loop, 519us/kernel) and r13 (64-bin global-atomic histogram: 364us/
// kernel) both reverted. Only addition: s_setprio(1) around gg's MFMA
// cluster (blocks sit in different phases -> scheduler arbitration pays).
// ---------------------------------------------------------------------------

typedef __bf16 bf16;
typedef __bf16 bf16x8 __attribute__((ext_vector_type(8)));
typedef float  f32x4  __attribute__((ext_vector_type(4)));

#define DEV __device__ __forceinline__

DEV f32x4 mfma16(bf16x8 a, bf16x8 b, f32x4 c) {
    return __builtin_amdgcn_mfma_f32_16x16x32_bf16(a, b, c, 0, 0, 0);
}

DEV bf16x8 load_a8(const float* p) {
    f32x4 lo = *(const f32x4*)p;
    f32x4 hi = *(const f32x4*)(p + 4);
    bf16x8 v;
    v[0] = (bf16)lo[0]; v[1] = (bf16)lo[1]; v[2] = (bf16)lo[2]; v[3] = (bf16)lo[3];
    v[4] = (bf16)hi[0]; v[5] = (bf16)hi[1]; v[6] = (bf16)hi[2]; v[7] = (bf16)hi[3];
    return v;
}
DEV bf16x8 load_a8(const bf16* p) { return *(const bf16x8*)p; }

// single fused f32->bf16 conversion of all 8 weight matrices into wb
__global__ void cvt8_kernel(const float* s0, const float* s1, const float* s2, const float* s3,
                            const float* s4, const float* s5, const float* s6, const float* s7,
                            bf16* __restrict__ wb) {
    const int i = blockIdx.x * 256 + threadIdx.x;
    if (i >= 294912) return;
    float v;
    if      (i < 32768)  v = s0[i];
    else if (i < 65536)  v = s1[i - 32768];
    else if (i < 81920)  v = s2[i - 65536];
    else if (i < 98304)  v = s3[i - 81920];
    else if (i < 147456) v = s4[i - 98304];
    else if (i < 196608) v = s5[i - 147456];
    else if (i < 245760) v = s6[i - 196608];
    else                 v = s7[i - 245760];
    wb[i] = (bf16)v;
}

// ---------------------------------------------------------------------------
// GEMM: C[M,Co] = act(A[M,Ci] @ W[Co,Ci]^T + bias). 2 M-tiles/wave.
// MFMA 16x16x32 bf16; C/D layout (m89): col=lane&15, row=4*(lane>>4)+j.
// ---------------------------------------------------------------------------
template<int Ci, int Co, bool ACT, bool BIAS, typename AT, typename OT>
__global__ __launch_bounds__(256) void gemm_kernel(
    const AT* __restrict__ A, const bf16* __restrict__ W,
    const float* __restrict__ bias, OT* __restrict__ C, int M)
{
    const int tid  = threadIdx.x;
    const int lane = tid & 63, w = tid >> 6;
    const int lr   = lane & 15, ko = lane >> 4;
    const int rbase = blockIdx.x * 128 + w * 32;

    constexpr int KC = Ci / 32;
    constexpr int NT = Co / 16;

    bf16x8 a[2][KC];
#pragma unroll
    for (int m = 0; m < 2; ++m) {
        long arow = rbase + m * 16 + lr; if (arow > M - 1) arow = M - 1;  // clamped rows never stored
#pragma unroll
        for (int kc = 0; kc < KC; ++kc)
            a[m][kc] = load_a8(A + arow * Ci + kc * 32 + ko * 8);
    }

#pragma unroll
    for (int t = 0; t < NT; ++t) {
        f32x4 acc0 = {0.f, 0.f, 0.f, 0.f};
        f32x4 acc1 = {0.f, 0.f, 0.f, 0.f};
        const bf16* wp = W + (long)(t * 16 + lr) * Ci + ko * 8;
#pragma unroll
        for (int kc = 0; kc < KC; ++kc) {
            bf16x8 wf = *(const bf16x8*)(wp + kc * 32);
            acc0 = mfma16(a[0][kc], wf, acc0);
            acc1 = mfma16(a[1][kc], wf, acc1);
        }

        const int col = t * 16 + lr;
        float bv = 0.f;
        if (BIAS) bv = bias[col];
#pragma unroll
        for (int j = 0; j < 4; ++j) {
            const int r0 = rbase + ko * 4 + j;
            if (r0 < M) {
                float v = acc0[j] + bv;
                if (ACT) v = (v >= 0.f) ? v : 0.01f * v;
                C[(long)r0 * Co + col] = (OT)v;
            }
            const int r1 = rbase + 16 + ko * 4 + j;
            if (r1 < M) {
                float v = acc1[j] + bv;
                if (ACT) v = (v >= 0.f) ? v : 0.01f * v;
                C[(long)r1 * Co + col] = (OT)v;
            }
        }
    }
}

// ---------------------------------------------------------------------------
// GRUCell, 64-row blocks (4 waves x 16 rows), LDS weight tiles + reg prefetch.
// Safe for out == x (f32 path): all A-frag reads precede the first barrier.
// ---------------------------------------------------------------------------
template<typename XT>
__global__ __launch_bounds__(256) void gru_kernel(
    const XT* x, const float* __restrict__ hp,
    const bf16* __restrict__ wih, const bf16* __restrict__ whh,
    const float* __restrict__ bih, const float* __restrict__ bhh,
    float* out, int N)
{
    __shared__ bf16 Lw[6][16][128];   // 24 KB

    const int tid  = threadIdx.x;
    const int lane = tid & 63, w = tid >> 6;
    const int lr   = lane & 15, ko = lane >> 4;
    const long rbase = (long)blockIdx.x * 64 + w * 16;

    long arow = rbase + lr; if (arow > N - 1) arow = N - 1;
    bf16x8 ax[4], ah[4];
#pragma unroll
    for (int kc = 0; kc < 4; ++kc) {
        ax[kc] = load_a8(x  + arow * 128 + kc * 32 + ko * 8);
        ah[kc] = load_a8(hp + arow * 128 + kc * 32 + ko * 8);
    }

    bf16x8 pre[6];
    auto LDW = [&](int tc) {
#pragma unroll
        for (int i = 0; i < 6; ++i) {
            const int ch  = tid + 256 * i;
            const int g   = ch >> 8, rem = ch & 255;
            const int row = rem >> 4, cc = rem & 15;
            const int scc = cc ^ (row & 7);
            pre[i] = *(const bf16x8*)((g < 3 ? wih : whh)
                + (long)(((g % 3) * 128 + tc * 16 + row) * 128 + scc * 8));
        }
    };
    LDW(0);

    for (int tc = 0; tc < 8; ++tc) {
        __syncthreads();
#pragma unroll
        for (int i = 0; i < 6; ++i) {
            const int ch  = tid + 256 * i;
            const int g   = ch >> 8, rem = ch & 255;
            const int row = rem >> 4, cc = rem & 15;
            *(bf16x8*)(&Lw[g][row][cc * 8]) = pre[i];
        }
        __syncthreads();
        if (tc < 7) LDW(tc + 1);

        const int col = tc * 16 + lr;
        const float br = bih[col]       + bhh[col];
        const float bz = bih[128 + col] + bhh[128 + col];
        const float bi = bih[256 + col];
        const float bh = bhh[256 + col];

        f32x4 ar = {0.f, 0.f, 0.f, 0.f};
        f32x4 az = {0.f, 0.f, 0.f, 0.f};
        f32x4 ai = {0.f, 0.f, 0.f, 0.f};
        f32x4 ag = {0.f, 0.f, 0.f, 0.f};
#pragma unroll
        for (int kc = 0; kc < 4; ++kc) {
            const int cc = (kc * 4 + ko) ^ (lr & 7);
            bf16x8 wr_i = *(const bf16x8*)(&Lw[0][lr][cc * 8]);
            bf16x8 wz_i = *(const bf16x8*)(&Lw[1][lr][cc * 8]);
            bf16x8 wn_i = *(const bf16x8*)(&Lw[2][lr][cc * 8]);
            bf16x8 wr_h = *(const bf16x8*)(&Lw[3][lr][cc * 8]);
            bf16x8 wz_h = *(const bf16x8*)(&Lw[4][lr][cc * 8]);
            bf16x8 wn_h = *(const bf16x8*)(&Lw[5][lr][cc * 8]);
            ar = mfma16(ax[kc], wr_i, ar);
            ar = mfma16(ah[kc], wr_h, ar);
            az = mfma16(ax[kc], wz_i, az);
            az = mfma16(ah[kc], wz_h, az);
            ai = mfma16(ax[kc], wn_i, ai);
            ag = mfma16(ah[kc], wn_h, ag);
        }
#pragma unroll
        for (int j = 0; j < 4; ++j) {
            const long row = rbase + ko * 4 + j;
            if (row < N) {
                const float r = 1.f / (1.f + __expf(-(ar[j] + br)));
                const float z = 1.f / (1.f + __expf(-(az[j] + bz)));
                const float pre_ = (ai[j] + bi) + r * (ag[j] + bh);
                const float n = 1.f - 2.f / (1.f + __expf(2.f * pre_));
                out[row * 128 + col] = (1.f - z) * n + z * hp[row * 128 + col];
            }
        }
    }
}

// ---------------------------------------------------------------------------
// FUSED gather + GRU: conv output h computed per-lane directly in the MFMA
// A-fragment layout (lane owns row lane&15, cols (lane>>4)*8 + kc*32).
// setprio(1) around the MFMA cluster: gg blocks on a CU sit in different
// phases (gather VALU vs GRU MFMA), so priority arbitration pays (T5).
// ---------------------------------------------------------------------------
__global__ __launch_bounds__(256) void gg_kernel(
    const bf16* __restrict__ xwb,
    const int* __restrict__ rowptr, const int* __restrict__ degi,
    const int* __restrict__ csr_src, const float* __restrict__ csr_norm,
    const float* __restrict__ dinv, const float* __restrict__ cbias,
    const float* __restrict__ hp,
    const bf16* __restrict__ wih, const bf16* __restrict__ whh,
    const float* __restrict__ bih, const float* __restrict__ bhh,
    float* __restrict__ out, int N)
{
    __shared__ bf16 Lw[6][16][128];   // 24 KB

    const int tid  = threadIdx.x;
    const int lane = tid & 63, w = tid >> 6;
    const int lr   = lane & 15, ko = lane >> 4;
    const long rbase = (long)blockIdx.x * 64 + w * 16;

    long arow = rbase + lr; if (arow > N - 1) arow = N - 1;

    // ---- gather phase ----
    float acc[4][8];
#pragma unroll
    for (int kc = 0; kc < 4; ++kc)
#pragma unroll
        for (int j = 0; j < 8; ++j) acc[kc][j] = 0.f;
    {
        const int start = rowptr[arow];
        const int deg   = degi[arow];
        const bf16* xb  = xwb + ko * 8;
        for (int k = 0; k < deg; ++k) {
            const int   s  = csr_src[start + k];
            const float nm = csr_norm[start + k];
            const bf16* vp = xb + (long)s * 128;
            bf16x8 v0 = *(const bf16x8*)(vp);
            bf16x8 v1 = *(const bf16x8*)(vp + 32);
            bf16x8 v2 = *(const bf16x8*)(vp + 64);
            bf16x8 v3 = *(const bf16x8*)(vp + 96);
#pragma unroll
            for (int j = 0; j < 8; ++j) {
                acc[0][j] += (float)v0[j] * nm;
                acc[1][j] += (float)v1[j] * nm;
                acc[2][j] += (float)v2[j] * nm;
                acc[3][j] += (float)v3[j] * nm;
            }
        }
    }

    bf16x8 ax[4], ah[4];
    {
        const float di = dinv[arow], sl = di * di;
        const bf16* vp = xwb + (long)arow * 128 + ko * 8;
#pragma unroll
        for (int kc = 0; kc < 4; ++kc) {
            bf16x8 vd = *(const bf16x8*)(vp + kc * 32);
#pragma unroll
            for (int j = 0; j < 8; ++j) {
                float t = acc[kc][j] + (float)vd[j] * sl + cbias[kc * 32 + ko * 8 + j];
                t = (t >= 0.f) ? t : 0.01f * t;
                ax[kc][j] = (bf16)t;
            }
            ah[kc] = load_a8(hp + arow * 128 + kc * 32 + ko * 8);
        }
    }

    // ---- GRU phase ----
    bf16x8 pre[6];
    auto LDW = [&](int tc) {
#pragma unroll
        for (int i = 0; i < 6; ++i) {
            const int ch  = tid + 256 * i;
            const int g   = ch >> 8, rem = ch & 255;
            const int row = rem >> 4, cc = rem & 15;
            const int scc = cc ^ (row & 7);
            pre[i] = *(const bf16x8*)((g < 3 ? wih : whh)
                + (long)(((g % 3) * 128 + tc * 16 + row) * 128 + scc * 8));
        }
    };
    LDW(0);

    for (int tc = 0; tc < 8; ++tc) {
        __syncthreads();
#pragma unroll
        for (int i = 0; i < 6; ++i) {
            const int ch  = tid + 256 * i;
            const int g   = ch >> 8, rem = ch & 255;
            const int row = rem >> 4, cc = rem & 15;
            *(bf16x8*)(&Lw[g][row][cc * 8]) = pre[i];
        }
        __syncthreads();
        if (tc < 7) LDW(tc + 1);

        const int col = tc * 16 + lr;
        const float br = bih[col]       + bhh[col];
        const float bz = bih[128 + col] + bhh[128 + col];
        const float bi = bih[256 + col];
        const float bh = bhh[256 + col];

        f32x4 ar = {0.f, 0.f, 0.f, 0.f};
        f32x4 az = {0.f, 0.f, 0.f, 0.f};
        f32x4 ai = {0.f, 0.f, 0.f, 0.f};
        f32x4 ag = {0.f, 0.f, 0.f, 0.f};
        __builtin_amdgcn_s_setprio(1);
#pragma unroll
        for (int kc = 0; kc < 4; ++kc) {
            const int cc = (kc * 4 + ko) ^ (lr & 7);
            bf16x8 wr_i = *(const bf16x8*)(&Lw[0][lr][cc * 8]);
            bf16x8 wz_i = *(const bf16x8*)(&Lw[1][lr][cc * 8]);
            bf16x8 wn_i = *(const bf16x8*)(&Lw[2][lr][cc * 8]);
            bf16x8 wr_h = *(const bf16x8*)(&Lw[3][lr][cc * 8]);
            bf16x8 wz_h = *(const bf16x8*)(&Lw[4][lr][cc * 8]);
            bf16x8 wn_h = *(const bf16x8*)(&Lw[5][lr][cc * 8]);
            ar = mfma16(ax[kc], wr_i, ar);
            ar = mfma16(ah[kc], wr_h, ar);
            az = mfma16(ax[kc], wz_i, az);
            az = mfma16(ah[kc], wz_h, az);
            ai = mfma16(ax[kc], wn_i, ai);
            ag = mfma16(ah[kc], wn_h, ag);
        }
        __builtin_amdgcn_s_setprio(0);
#pragma unroll
        for (int j = 0; j < 4; ++j) {
            const long row = rbase + ko * 4 + j;
            if (row < N) {
                const float r = 1.f / (1.f + __expf(-(ar[j] + br)));
                const float z = 1.f / (1.f + __expf(-(az[j] + bz)));
                const float pre_ = (ai[j] + bi) + r * (ag[j] + bh);
                const float n = 1.f - 2.f / (1.f + __expf(2.f * pre_));
                out[row * 128 + col] = (1.f - z) * n + z * hp[row * 128 + col];
            }
        }
    }
}

// ---------------------------------------------------------------------------
// CSR build chain (kernel-boundary sync; NO grid.sync -- ~100us each on 8 XCDs.
// NO concentrated atomics -- 64-bin global histogram cost 364us in r13.)
// ---------------------------------------------------------------------------
__global__ void deg_kernel(const int* __restrict__ dst, int* degi, int E) {
    const int e = blockIdx.x * 256 + threadIdx.x;
    if (e < E) atomicAdd(&degi[dst[e]], 1);
}
__global__ void scan1_kernel(const int* __restrict__ degi, int* __restrict__ inc,
                             int* __restrict__ bsum, float* __restrict__ dinv, int N) {
    __shared__ int s[256];
    const int i = blockIdx.x * 256 + threadIdx.x;
    const int d = (i < N) ? degi[i] : 0;
    if (i < N) dinv[i] = rsqrtf((float)d + 1.0f);   // +1 self loop
    s[threadIdx.x] = d;
    __syncthreads();
#pragma unroll
    for (int off = 1; off < 256; off <<= 1) {
        int t = (threadIdx.x >= off) ? s[threadIdx.x - off] : 0;
        __syncthreads();
        s[threadIdx.x] += t;
        __syncthreads();
    }
    if (i < N) inc[i] = s[threadIdx.x];
    if (threadIdx.x == 255) bsum[blockIdx.x] = s[255];
}
__global__ void scan2_kernel(int* bsum, int nb) {
    __shared__ int s[512];
    __shared__ int carry;
    if (threadIdx.x == 0) carry = 0;
    __syncthreads();
    for (int base = 0; base < nb; base += 512) {
        const int i = base + threadIdx.x;
        s[threadIdx.x] = (i < nb) ? bsum[i] : 0;
        __syncthreads();
#pragma unroll
        for (int off = 1; off < 512; off <<= 1) {
            int t = (threadIdx.x >= off) ? s[threadIdx.x - off] : 0;
            __syncthreads();
            s[threadIdx.x] += t;
            __syncthreads();
        }
        const int c = carry;
        if (i < nb) bsum[i] = s[threadIdx.x] + c;
        __syncthreads();
        if (threadIdx.x == 511) carry = c + s[511];
        __syncthreads();
    }
}
__global__ void scan3_kernel(const int* __restrict__ inc, const int* __restrict__ degi,
                             const int* __restrict__ bsum, int* __restrict__ rowptr,
                             int* __restrict__ rp2, int N) {
    const int i = blockIdx.x * 256 + threadIdx.x;
    if (i >= N) return;
    const int prev = (blockIdx.x > 0) ? bsum[blockIdx.x - 1] : 0;
    const int rp = prev + inc[i] - degi[i];   // exclusive prefix
    rowptr[i] = rp;
    rp2[i]    = rp;
}
__global__ void fill_kernel(const int* __restrict__ src, const int* __restrict__ dst,
                            int* rp2, const float* __restrict__ dinv,
                            int* __restrict__ csr_src, float* __restrict__ csr_norm, int E) {
    const int e = blockIdx.x * 256 + threadIdx.x;
    if (e >= E) return;
    const int s = src[e], d = dst[e];
    const int pos = atomicAdd(&rp2[d], 1);
    csr_src[pos]  = s;
    csr_norm[pos] = dinv[s] * dinv[d];
}

// ---------------------------------------------------------------------------
// Standalone gather (fallback path for small ws / column passes)
// ---------------------------------------------------------------------------
template<typename OT>
__global__ __launch_bounds__(256) void gather_kernel(
    const bf16* __restrict__ xwb,
    const int* __restrict__ rowptr, const int* __restrict__ degi,
    const int* __restrict__ csr_src, const float* __restrict__ csr_norm,
    const float* __restrict__ dinv, const float* __restrict__ bias,
    OT* __restrict__ out, int N, int colbase, int cw, int lg)
{
    const long tid = (long)blockIdx.x * 256 + threadIdx.x;
    const long d = tid >> lg;
    const int  c = (int)(tid & ((1 << lg) - 1));
    if (d >= N) return;

    const int start = rowptr[d];
    const int deg   = degi[d];
    const int h     = deg >> 1;
    const bf16* xb  = xwb + c * 8;

    float acca[8] = {0.f, 0.f, 0.f, 0.f, 0.f, 0.f, 0.f, 0.f};
    float accb[8] = {0.f, 0.f, 0.f, 0.f, 0.f, 0.f, 0.f, 0.f};
    for (int k = 0; k < h; ++k) {
        const int   sa = csr_src[start + k];
        const int   sb = csr_src[start + h + k];
        const float na = csr_norm[start + k];
        const float nb_ = csr_norm[start + h + k];
        bf16x8 va = *(const bf16x8*)(xb + (long)sa * cw);
        bf16x8 vb = *(const bf16x8*)(xb + (long)sb * cw);
#pragma unroll
        for (int j = 0; j < 8; ++j) {
            acca[j] += (float)va[j] * na;
            accb[j] += (float)vb[j] * nb_;
        }
    }
    if (deg & 1) {
        const int   s  = csr_src[start + deg - 1];
        const float nm = csr_norm[start + deg - 1];
        bf16x8 v = *(const bf16x8*)(xb + (long)s * cw);
#pragma unroll
        for (int j = 0; j < 8; ++j) acca[j] += (float)v[j] * nm;
    }

    const float di = dinv[d], sl = di * di;
    bf16x8 vd = *(const bf16x8*)(xb + d * cw);
    const int col = colbase + c * 8;
    float v[8];
#pragma unroll
    for (int j = 0; j < 8; ++j) {
        float t = acca[j] + accb[j] + (float)vd[j] * sl + bias[col + j];
        v[j] = (t >= 0.f) ? t : 0.01f * t;
    }
    if constexpr (std::is_same<OT, bf16>::value) {
        bf16x8 o;
#pragma unroll
        for (int j = 0; j < 8; ++j) o[j] = (bf16)v[j];
        *(bf16x8*)(out + d * 128 + col) = o;
    } else {
        f32x4 o0, o1;
#pragma unroll
        for (int j = 0; j < 4; ++j) { o0[j] = v[j]; o1[j] = v[4 + j]; }
        *(f32x4*)(out + d * 128 + col)     = o0;
        *(f32x4*)(out + d * 128 + col + 4) = o1;
    }
}

// ---------------------------------------------------------------------------
// LP head: 16 lanes per edge, shfl reduce.
// ---------------------------------------------------------------------------
__global__ __launch_bounds__(256) void lp_kernel(
    const float* __restrict__ emb, const int* __restrict__ eli,
    const float* __restrict__ wpost, const float* __restrict__ bpost,
    float* __restrict__ logits, int EL)
{
    const long t = (long)blockIdx.x * 256 + threadIdx.x;
    const long e = t >> 4;
    const int  c = (int)(t & 15);
    if (e >= EL) return;
    const long s = eli[e], d = eli[EL + e];

    f32x4 a0 = *(const f32x4*)(emb + s * 128 + c * 8);
    f32x4 a1 = *(const f32x4*)(emb + s * 128 + c * 8 + 4);
    f32x4 b0 = *(const f32x4*)(emb + d * 128 + c * 8);
    f32x4 b1 = *(const f32x4*)(emb + d * 128 + c * 8 + 4);
    f32x4 w00 = *(const f32x4*)(wpost + c * 8);
    f32x4 w01 = *(const f32x4*)(wpost + c * 8 + 4);
    f32x4 w10 = *(const f32x4*)(wpost + 128 + c * 8);
    f32x4 w11 = *(const f32x4*)(wpost + 128 + c * 8 + 4);

    float acc = 0.f;
#pragma unroll
    for (int i = 0; i < 4; ++i) {
        acc += a0[i] * b0[i] * (w00[i] + w10[i]);
        acc += a1[i] * b1[i] * (w01[i] + w11[i]);
    }
#pragma unroll
    for (int m = 1; m < 16; m <<= 1) acc += __shfl_xor(acc, m);
    if (c == 0) logits[e] = acc + bpost[0] + bpost[1];
}

// ---------------------------------------------------------------------------
extern "C" void kernel_launch(void* const* d_in, const int* in_sizes, int n_in,
                              void* d_out, int out_size, void* d_ws, size_t ws_size,
                              hipStream_t stream) {
    const float* x      = (const float*)d_in[0];
    const int*   ei     = (const int*)d_in[1];   // [2,E]: row0=src, row1=dst
    const int*   eli    = (const int*)d_in[2];
    const float* prev0  = (const float*)d_in[3];
    const float* prev1  = (const float*)d_in[4];
    const float* w_pre1 = (const float*)d_in[5];
    const float* b_pre1 = (const float*)d_in[6];
    const float* w_pre2 = (const float*)d_in[7];
    const float* b_pre2 = (const float*)d_in[8];
    const float* w_c1   = (const float*)d_in[9];
    const float* b_c1   = (const float*)d_in[10];
    const float* w_c2   = (const float*)d_in[11];
    const float* b_c2   = (const float*)d_in[12];
    const float* w_post = (const float*)d_in[13];
    const float* b_post = (const float*)d_in[14];
    const float* g1_wih = (const float*)d_in[15];
    const float* g1_whh = (const float*)d_in[16];
    const float* g1_bih = (const float*)d_in[17];
    const float* g1_bhh = (const float*)d_in[18];
    const float* g2_wih = (const float*)d_in[19];
    const float* g2_whh = (const float*)d_in[20];
    const float* g2_bih = (const float*)d_in[21];
    const float* g2_bhh = (const float*)d_in[22];

    const int N  = in_sizes[0] / 128;
    const int E  = in_sizes[1] / 2;
    const int EL = in_sizes[2] / 2;
    const long NH = (long)N * 128;

    // outputs (f32)
    float* out    = (float*)d_out;
    float* logits = out;
    float* emb0   = out + EL;
    float* emb1   = emb0 + NH;
    float* emb2   = emb1 + NH;

    // bf16 intermediates in currently-dead output slots
    bf16* H1b = (bf16*)emb1;   // [N,256] bf16 == emb1 slot
    bf16* H2b = (bf16*)emb2;   // [N,128] bf16 (first half of emb2 slot)
    bf16* h1b = (bf16*)emb2;   // fallback only

    // ---- workspace layout ----
    char* ws = (char*)d_ws;
    size_t p = 0;
    auto alloc = [&](size_t bytes) { size_t o = p; p = (p + bytes + 255) & ~(size_t)255; return o; };
    float* dinv    = (float*)(ws + alloc((size_t)N * 4));
    int*   degi    = (int*)  (ws + alloc((size_t)N * 4));
    int*   inc     = (int*)  (ws + alloc((size_t)N * 4));
    int*   rowptr  = (int*)  (ws + alloc((size_t)(N + 1) * 4));
    int*   rp2     = (int*)  (ws + alloc((size_t)N * 4));
    int*   bsum    = (int*)  (ws + alloc(4096));
    bf16*  wb      = (bf16*) (ws + alloc((size_t)294912 * 2));
    int*   csr_src = (int*)  (ws + alloc((size_t)E * 4));
    float* csr_nrm = (float*)(ws + alloc((size_t)E * 4));
    const size_t fixed = p;
    bf16*  xwb     = (bf16*)(ws + fixed);

    int cw = 128;
    while (cw > 16 && fixed + (size_t)N * cw * 2 > ws_size) cw >>= 1;
    const int lg = __builtin_ctz(cw >> 3);
    const int passes = 128 / cw;
    const bool fused = (cw == 128);
    const bool big_ws = fused &&
        (ws_size >= fixed + (size_t)N * 128 * 2 + (size_t)N * 128 * 2);
    bf16* h2b = big_ws ? (bf16*)(ws + fixed + (size_t)N * 128 * 2) : nullptr;

    bf16* wb_pre1 = wb;
    bf16* wb_pre2 = wb_pre1 + 32768;
    bf16* wb_c1   = wb_pre2 + 32768;
    bf16* wb_c2   = wb_c1 + 16384;
    bf16* wb_g1i  = wb_c2 + 16384;
    bf16* wb_g1h  = wb_g1i + 49152;
    bf16* wb_g2i  = wb_g1h + 49152;
    bf16* wb_g2h  = wb_g2i + 49152;

    const int gB = 256;
    const dim3 blk(gB);
    const int grid_rows128 = (N + 127) / 128;
    const int grid_gru     = (N + 63) / 64;
    const int grid_E       = (E + gB - 1) / gB;
    const int nb           = (N + 255) / 256;

    cvt8_kernel<<<(294912 + 255) / 256, blk, 0, stream>>>(
        w_pre1, w_pre2, w_c1, w_c2, g1_wih, g1_whh, g2_wih, g2_whh, wb);

    // ---- CSR build ----
    hipMemsetAsync(degi, 0, (size_t)N * 4, stream);
    deg_kernel<<<grid_E, blk, 0, stream>>>(ei + E, degi, E);
    scan1_kernel<<<nb, blk, 0, stream>>>(degi, inc, bsum, dinv, N);
    scan2_kernel<<<1, 512, 0, stream>>>(bsum, nb);
    scan3_kernel<<<nb, blk, 0, stream>>>(inc, degi, bsum, rowptr, rp2, N);
    fill_kernel<<<grid_E, blk, 0, stream>>>(ei, ei + E, rp2, dinv, csr_src, csr_nrm, E);

    // ---- preprocess: x -> H1b (bf16) -> H2b (bf16) ----
    gemm_kernel<128, 256, true, true, float, bf16><<<grid_rows128, blk, 0, stream>>>(x, wb_pre1, b_pre1, H1b, N);
    gemm_kernel<256, 128, true, true, bf16,  bf16><<<grid_rows128, blk, 0, stream>>>(H1b, wb_pre2, b_pre2, H2b, N);

    // GRU1: emb0 = gru(H2b, prev0)
    gru_kernel<bf16><<<grid_gru, blk, 0, stream>>>(H2b, prev0, wb_g1i, wb_g1h, g1_bih, g1_bhh, emb0, N);

    auto run_gemm = [&](const float* hin, const bf16* wp) {
        switch (cw) {
        case 128: gemm_kernel<128, 128, false, false, float, bf16><<<grid_rows128, blk, 0, stream>>>(hin, wp, nullptr, xwb, N); break;
        case 64:  gemm_kernel<128, 64,  false, false, float, bf16><<<grid_rows128, blk, 0, stream>>>(hin, wp, nullptr, xwb, N); break;
        case 32:  gemm_kernel<128, 32,  false, false, float, bf16><<<grid_rows128, blk, 0, stream>>>(hin, wp, nullptr, xwb, N); break;
        default:  gemm_kernel<128, 16,  false, false, float, bf16><<<grid_rows128, blk, 0, stream>>>(hin, wp, nullptr, xwb, N); break;
        }
    };

    if (fused) {
        // conv1 + GRU2 fused: emb0 -> xwb -> (gather+gru) -> emb1
        run_gemm(emb0, wb_c1);
        gg_kernel<<<grid_gru, blk, 0, stream>>>(xwb, rowptr, degi, csr_src, csr_nrm,
                                                dinv, b_c1, prev0,
                                                wb_g1i, wb_g1h, g1_bih, g1_bhh, emb1, N);
        // conv2 + GRU3 fused: emb1 -> xwb -> (gather+gru) -> emb2
        run_gemm(emb1, wb_c2);
        gg_kernel<<<grid_gru, blk, 0, stream>>>(xwb, rowptr, degi, csr_src, csr_nrm,
                                                dinv, b_c2, prev1,
                                                wb_g2i, wb_g2h, g2_bih, g2_bhh, emb2, N);
    } else {
        const int grid_ga = (int)((((long)N << lg) + gB - 1) / gB);
        for (int ps = 0; ps < passes; ++ps) {
            run_gemm(emb0, wb_c1 + (size_t)(ps * cw) * 128);
            gather_kernel<bf16><<<grid_ga, blk, 0, stream>>>(xwb, rowptr, degi, csr_src, csr_nrm,
                                                             dinv, b_c1, h1b, N, ps * cw, cw, lg);
        }
        gru_kernel<bf16><<<grid_gru, blk, 0, stream>>>(h1b, prev0, wb_g1i, wb_g1h, g1_bih, g1_bhh, emb1, N);
        for (int ps = 0; ps < passes; ++ps) {
            run_gemm(emb1, wb_c2 + (size_t)(ps * cw) * 128);
            if (big_ws)
                gather_kernel<bf16><<<grid_ga, blk, 0, stream>>>(xwb, rowptr, degi, csr_src, csr_nrm,
                                                                 dinv, b_c2, h2b, N, ps * cw, cw, lg);
            else
                gather_kernel<float><<<grid_ga, blk, 0, stream>>>(xwb, rowptr, degi, csr_src, csr_nrm,
                                                                  dinv, b_c2, emb2, N, ps * cw, cw, lg);
        }
        if (big_ws)
            gru_kernel<bf16><<<grid_gru, blk, 0, stream>>>(h2b, prev1, wb_g2i, wb_g2h, g2_bih, g2_bhh, emb2, N);
        else
            gru_kernel<float><<<grid_gru, blk, 0, stream>>>(emb2, prev1, wb_g2i, wb_g2h, g2_bih, g2_bhh, emb2, N);
    }

    // LP head (16 lanes/edge)
    lp_kernel<<<(int)(((long)EL * 16 + gB - 1) / gB), blk, 0, stream>>>(emb2, eli, w_post, b_post, logits, EL);
}

// Round 15
// 531.473 us; speedup vs baseline: 2.4777x; 1.0103x over previous
//
#include <hip/hip_runtime.h>
#include <hip/hip_bf16.h>
#include <type_traits>

// ---------------------------------------------------------------------------
// ROLAND GNN forward. Buffers f32; matmuls bf16-MFMA, f32 accum.
// Outputs (concat, f32): logits[EL], emb0[N,128], emb1[N,128], emb2[N,128]
// Round 15: round-14 structure + gg gather MLP fix: packed int2 edge records
// (one 8B load per edge) and 2-edge unrolled gather (8 row-loads in flight).
// ---------------------------------------------------------------------------

typedef __bf16 bf16;
typedef __bf16 bf16x8 __attribute__((ext_vector_type(8)));
typedef float  f32x4  __attribute__((ext_vector_type(4)));

#define DEV __device__ __forceinline__

DEV f32x4 mfma16(bf16x8 a, bf16x8 b, f32x4 c) {
    return __builtin_amdgcn_mfma_f32_16x16x32_bf16(a, b, c, 0, 0, 0);
}

DEV bf16x8 load_a8(const float* p) {
    f32x4 lo = *(const f32x4*)p;
    f32x4 hi = *(const f32x4*)(p + 4);
    bf16x8 v;
    v[0] = (bf16)lo[0]; v[1] = (bf16)lo[1]; v[2] = (bf16)lo[2]; v[3] = (bf16)lo[3];
    v[4] = (bf16)hi[0]; v[5] = (bf16)hi[1]; v[6] = (bf16)hi[2]; v[7] = (bf16)hi[3];
    return v;
}
DEV bf16x8 load_a8(const bf16* p) { return *(const bf16x8*)p; }

// single fused f32->bf16 conversion of all 8 weight matrices into wb
__global__ void cvt8_kernel(const float* s0, const float* s1, const float* s2, const float* s3,
                            const float* s4, const float* s5, const float* s6, const float* s7,
                            bf16* __restrict__ wb) {
    const int i = blockIdx.x * 256 + threadIdx.x;
    if (i >= 294912) return;
    float v;
    if      (i < 32768)  v = s0[i];
    else if (i < 65536)  v = s1[i - 32768];
    else if (i < 81920)  v = s2[i - 65536];
    else if (i < 98304)  v = s3[i - 81920];
    else if (i < 147456) v = s4[i - 98304];
    else if (i < 196608) v = s5[i - 147456];
    else if (i < 245760) v = s6[i - 196608];
    else                 v = s7[i - 245760];
    wb[i] = (bf16)v;
}

// ---------------------------------------------------------------------------
// GEMM: C[M,Co] = act(A[M,Ci] @ W[Co,Ci]^T + bias). 2 M-tiles/wave.
// MFMA 16x16x32 bf16; C/D layout (m89): col=lane&15, row=4*(lane>>4)+j.
// ---------------------------------------------------------------------------
template<int Ci, int Co, bool ACT, bool BIAS, typename AT, typename OT>
__global__ __launch_bounds__(256) void gemm_kernel(
    const AT* __restrict__ A, const bf16* __restrict__ W,
    const float* __restrict__ bias, OT* __restrict__ C, int M)
{
    const int tid  = threadIdx.x;
    const int lane = tid & 63, w = tid >> 6;
    const int lr   = lane & 15, ko = lane >> 4;
    const int rbase = blockIdx.x * 128 + w * 32;

    constexpr int KC = Ci / 32;
    constexpr int NT = Co / 16;

    bf16x8 a[2][KC];
#pragma unroll
    for (int m = 0; m < 2; ++m) {
        long arow = rbase + m * 16 + lr; if (arow > M - 1) arow = M - 1;  // clamped rows never stored
#pragma unroll
        for (int kc = 0; kc < KC; ++kc)
            a[m][kc] = load_a8(A + arow * Ci + kc * 32 + ko * 8);
    }

#pragma unroll
    for (int t = 0; t < NT; ++t) {
        f32x4 acc0 = {0.f, 0.f, 0.f, 0.f};
        f32x4 acc1 = {0.f, 0.f, 0.f, 0.f};
        const bf16* wp = W + (long)(t * 16 + lr) * Ci + ko * 8;
#pragma unroll
        for (int kc = 0; kc < KC; ++kc) {
            bf16x8 wf = *(const bf16x8*)(wp + kc * 32);
            acc0 = mfma16(a[0][kc], wf, acc0);
            acc1 = mfma16(a[1][kc], wf, acc1);
        }

        const int col = t * 16 + lr;
        float bv = 0.f;
        if (BIAS) bv = bias[col];
#pragma unroll
        for (int j = 0; j < 4; ++j) {
            const int r0 = rbase + ko * 4 + j;
            if (r0 < M) {
                float v = acc0[j] + bv;
                if (ACT) v = (v >= 0.f) ? v : 0.01f * v;
                C[(long)r0 * Co + col] = (OT)v;
            }
            const int r1 = rbase + 16 + ko * 4 + j;
            if (r1 < M) {
                float v = acc1[j] + bv;
                if (ACT) v = (v >= 0.f) ? v : 0.01f * v;
                C[(long)r1 * Co + col] = (OT)v;
            }
        }
    }
}

// ---------------------------------------------------------------------------
// GRUCell, 64-row blocks (4 waves x 16 rows), LDS weight tiles + reg prefetch.
// Safe for out == x (f32 path): all A-frag reads precede the first barrier.
// ---------------------------------------------------------------------------
template<typename XT>
__global__ __launch_bounds__(256) void gru_kernel(
    const XT* x, const float* __restrict__ hp,
    const bf16* __restrict__ wih, const bf16* __restrict__ whh,
    const float* __restrict__ bih, const float* __restrict__ bhh,
    float* out, int N)
{
    __shared__ bf16 Lw[6][16][128];   // 24 KB

    const int tid  = threadIdx.x;
    const int lane = tid & 63, w = tid >> 6;
    const int lr   = lane & 15, ko = lane >> 4;
    const long rbase = (long)blockIdx.x * 64 + w * 16;

    long arow = rbase + lr; if (arow > N - 1) arow = N - 1;
    bf16x8 ax[4], ah[4];
#pragma unroll
    for (int kc = 0; kc < 4; ++kc) {
        ax[kc] = load_a8(x  + arow * 128 + kc * 32 + ko * 8);
        ah[kc] = load_a8(hp + arow * 128 + kc * 32 + ko * 8);
    }

    bf16x8 pre[6];
    auto LDW = [&](int tc) {
#pragma unroll
        for (int i = 0; i < 6; ++i) {
            const int ch  = tid + 256 * i;
            const int g   = ch >> 8, rem = ch & 255;
            const int row = rem >> 4, cc = rem & 15;
            const int scc = cc ^ (row & 7);
            pre[i] = *(const bf16x8*)((g < 3 ? wih : whh)
                + (long)(((g % 3) * 128 + tc * 16 + row) * 128 + scc * 8));
        }
    };
    LDW(0);

    for (int tc = 0; tc < 8; ++tc) {
        __syncthreads();
#pragma unroll
        for (int i = 0; i < 6; ++i) {
            const int ch  = tid + 256 * i;
            const int g   = ch >> 8, rem = ch & 255;
            const int row = rem >> 4, cc = rem & 15;
            *(bf16x8*)(&Lw[g][row][cc * 8]) = pre[i];
        }
        __syncthreads();
        if (tc < 7) LDW(tc + 1);

        const int col = tc * 16 + lr;
        const float br = bih[col]       + bhh[col];
        const float bz = bih[128 + col] + bhh[128 + col];
        const float bi = bih[256 + col];
        const float bh = bhh[256 + col];

        f32x4 ar = {0.f, 0.f, 0.f, 0.f};
        f32x4 az = {0.f, 0.f, 0.f, 0.f};
        f32x4 ai = {0.f, 0.f, 0.f, 0.f};
        f32x4 ag = {0.f, 0.f, 0.f, 0.f};
#pragma unroll
        for (int kc = 0; kc < 4; ++kc) {
            const int cc = (kc * 4 + ko) ^ (lr & 7);
            bf16x8 wr_i = *(const bf16x8*)(&Lw[0][lr][cc * 8]);
            bf16x8 wz_i = *(const bf16x8*)(&Lw[1][lr][cc * 8]);
            bf16x8 wn_i = *(const bf16x8*)(&Lw[2][lr][cc * 8]);
            bf16x8 wr_h = *(const bf16x8*)(&Lw[3][lr][cc * 8]);
            bf16x8 wz_h = *(const bf16x8*)(&Lw[4][lr][cc * 8]);
            bf16x8 wn_h = *(const bf16x8*)(&Lw[5][lr][cc * 8]);
            ar = mfma16(ax[kc], wr_i, ar);
            ar = mfma16(ah[kc], wr_h, ar);
            az = mfma16(ax[kc], wz_i, az);
            az = mfma16(ah[kc], wz_h, az);
            ai = mfma16(ax[kc], wn_i, ai);
            ag = mfma16(ah[kc], wn_h, ag);
        }
#pragma unroll
        for (int j = 0; j < 4; ++j) {
            const long row = rbase + ko * 4 + j;
            if (row < N) {
                const float r = 1.f / (1.f + __expf(-(ar[j] + br)));
                const float z = 1.f / (1.f + __expf(-(az[j] + bz)));
                const float pre_ = (ai[j] + bi) + r * (ag[j] + bh);
                const float n = 1.f - 2.f / (1.f + __expf(2.f * pre_));
                out[row * 128 + col] = (1.f - z) * n + z * hp[row * 128 + col];
            }
        }
    }
}

// ---------------------------------------------------------------------------
// FUSED gather + GRU: conv output h computed per-lane directly in the MFMA
// A-fragment layout. Gather uses packed int2 edge records (one 8B load per
// edge) and 2-edge unrolling (8 independent row-loads in flight).
// ---------------------------------------------------------------------------
__global__ __launch_bounds__(256) void gg_kernel(
    const bf16* __restrict__ xwb,
    const int* __restrict__ rowptr, const int* __restrict__ degi,
    const int2* __restrict__ csr_pk,
    const float* __restrict__ dinv, const float* __restrict__ cbias,
    const float* __restrict__ hp,
    const bf16* __restrict__ wih, const bf16* __restrict__ whh,
    const float* __restrict__ bih, const float* __restrict__ bhh,
    float* __restrict__ out, int N)
{
    __shared__ bf16 Lw[6][16][128];   // 24 KB

    const int tid  = threadIdx.x;
    const int lane = tid & 63, w = tid >> 6;
    const int lr   = lane & 15, ko = lane >> 4;
    const long rbase = (long)blockIdx.x * 64 + w * 16;

    long arow = rbase + lr; if (arow > N - 1) arow = N - 1;

    // ---- gather phase: 2-edge unrolled, packed records ----
    float acc[4][8];
#pragma unroll
    for (int kc = 0; kc < 4; ++kc)
#pragma unroll
        for (int j = 0; j < 8; ++j) acc[kc][j] = 0.f;
    {
        const int start = rowptr[arow];
        const int deg   = degi[arow];
        const bf16* xb  = xwb + ko * 8;
        int k = 0;
        for (; k + 2 <= deg; k += 2) {
            const int2 p0 = csr_pk[start + k];
            const int2 p1 = csr_pk[start + k + 1];
            const float nm0 = __int_as_float(p0.y);
            const float nm1 = __int_as_float(p1.y);
            const bf16* vp0 = xb + (long)p0.x * 128;
            const bf16* vp1 = xb + (long)p1.x * 128;
            bf16x8 a0 = *(const bf16x8*)(vp0);
            bf16x8 a1 = *(const bf16x8*)(vp0 + 32);
            bf16x8 a2 = *(const bf16x8*)(vp0 + 64);
            bf16x8 a3 = *(const bf16x8*)(vp0 + 96);
            bf16x8 b0 = *(const bf16x8*)(vp1);
            bf16x8 b1 = *(const bf16x8*)(vp1 + 32);
            bf16x8 b2 = *(const bf16x8*)(vp1 + 64);
            bf16x8 b3 = *(const bf16x8*)(vp1 + 96);
#pragma unroll
            for (int j = 0; j < 8; ++j) {
                acc[0][j] += (float)a0[j] * nm0 + (float)b0[j] * nm1;
                acc[1][j] += (float)a1[j] * nm0 + (float)b1[j] * nm1;
                acc[2][j] += (float)a2[j] * nm0 + (float)b2[j] * nm1;
                acc[3][j] += (float)a3[j] * nm0 + (float)b3[j] * nm1;
            }
        }
        if (k < deg) {
            const int2 p0 = csr_pk[start + k];
            const float nm0 = __int_as_float(p0.y);
            const bf16* vp0 = xb + (long)p0.x * 128;
            bf16x8 a0 = *(const bf16x8*)(vp0);
            bf16x8 a1 = *(const bf16x8*)(vp0 + 32);
            bf16x8 a2 = *(const bf16x8*)(vp0 + 64);
            bf16x8 a3 = *(const bf16x8*)(vp0 + 96);
#pragma unroll
            for (int j = 0; j < 8; ++j) {
                acc[0][j] += (float)a0[j] * nm0;
                acc[1][j] += (float)a1[j] * nm0;
                acc[2][j] += (float)a2[j] * nm0;
                acc[3][j] += (float)a3[j] * nm0;
            }
        }
    }

    bf16x8 ax[4], ah[4];
    {
        const float di = dinv[arow], sl = di * di;
        const bf16* vp = xwb + (long)arow * 128 + ko * 8;
#pragma unroll
        for (int kc = 0; kc < 4; ++kc) {
            bf16x8 vd = *(const bf16x8*)(vp + kc * 32);
#pragma unroll
            for (int j = 0; j < 8; ++j) {
                float t = acc[kc][j] + (float)vd[j] * sl + cbias[kc * 32 + ko * 8 + j];
                t = (t >= 0.f) ? t : 0.01f * t;
                ax[kc][j] = (bf16)t;
            }
            ah[kc] = load_a8(hp + arow * 128 + kc * 32 + ko * 8);
        }
    }

    // ---- GRU phase ----
    bf16x8 pre[6];
    auto LDW = [&](int tc) {
#pragma unroll
        for (int i = 0; i < 6; ++i) {
            const int ch  = tid + 256 * i;
            const int g   = ch >> 8, rem = ch & 255;
            const int row = rem >> 4, cc = rem & 15;
            const int scc = cc ^ (row & 7);
            pre[i] = *(const bf16x8*)((g < 3 ? wih : whh)
                + (long)(((g % 3) * 128 + tc * 16 + row) * 128 + scc * 8));
        }
    };
    LDW(0);

    for (int tc = 0; tc < 8; ++tc) {
        __syncthreads();
#pragma unroll
        for (int i = 0; i < 6; ++i) {
            const int ch  = tid + 256 * i;
            const int g   = ch >> 8, rem = ch & 255;
            const int row = rem >> 4, cc = rem & 15;
            *(bf16x8*)(&Lw[g][row][cc * 8]) = pre[i];
        }
        __syncthreads();
        if (tc < 7) LDW(tc + 1);

        const int col = tc * 16 + lr;
        const float br = bih[col]       + bhh[col];
        const float bz = bih[128 + col] + bhh[128 + col];
        const float bi = bih[256 + col];
        const float bh = bhh[256 + col];

        f32x4 ar = {0.f, 0.f, 0.f, 0.f};
        f32x4 az = {0.f, 0.f, 0.f, 0.f};
        f32x4 ai = {0.f, 0.f, 0.f, 0.f};
        f32x4 ag = {0.f, 0.f, 0.f, 0.f};
        __builtin_amdgcn_s_setprio(1);
#pragma unroll
        for (int kc = 0; kc < 4; ++kc) {
            const int cc = (kc * 4 + ko) ^ (lr & 7);
            bf16x8 wr_i = *(const bf16x8*)(&Lw[0][lr][cc * 8]);
            bf16x8 wz_i = *(const bf16x8*)(&Lw[1][lr][cc * 8]);
            bf16x8 wn_i = *(const bf16x8*)(&Lw[2][lr][cc * 8]);
            bf16x8 wr_h = *(const bf16x8*)(&Lw[3][lr][cc * 8]);
            bf16x8 wz_h = *(const bf16x8*)(&Lw[4][lr][cc * 8]);
            bf16x8 wn_h = *(const bf16x8*)(&Lw[5][lr][cc * 8]);
            ar = mfma16(ax[kc], wr_i, ar);
            ar = mfma16(ah[kc], wr_h, ar);
            az = mfma16(ax[kc], wz_i, az);
            az = mfma16(ah[kc], wz_h, az);
            ai = mfma16(ax[kc], wn_i, ai);
            ag = mfma16(ah[kc], wn_h, ag);
        }
        __builtin_amdgcn_s_setprio(0);
#pragma unroll
        for (int j = 0; j < 4; ++j) {
            const long row = rbase + ko * 4 + j;
            if (row < N) {
                const float r = 1.f / (1.f + __expf(-(ar[j] + br)));
                const float z = 1.f / (1.f + __expf(-(az[j] + bz)));
                const float pre_ = (ai[j] + bi) + r * (ag[j] + bh);
                const float n = 1.f - 2.f / (1.f + __expf(2.f * pre_));
                out[row * 128 + col] = (1.f - z) * n + z * hp[row * 128 + col];
            }
        }
    }
}

// ---------------------------------------------------------------------------
// CSR build chain (kernel-boundary sync; NO grid.sync; NO concentrated atomics)
// ---------------------------------------------------------------------------
__global__ void deg_kernel(const int* __restrict__ dst, int* degi, int E) {
    const int e = blockIdx.x * 256 + threadIdx.x;
    if (e < E) atomicAdd(&degi[dst[e]], 1);
}
__global__ void scan1_kernel(const int* __restrict__ degi, int* __restrict__ inc,
                             int* __restrict__ bsum, float* __restrict__ dinv, int N) {
    __shared__ int s[256];
    const int i = blockIdx.x * 256 + threadIdx.x;
    const int d = (i < N) ? degi[i] : 0;
    if (i < N) dinv[i] = rsqrtf((float)d + 1.0f);   // +1 self loop
    s[threadIdx.x] = d;
    __syncthreads();
#pragma unroll
    for (int off = 1; off < 256; off <<= 1) {
        int t = (threadIdx.x >= off) ? s[threadIdx.x - off] : 0;
        __syncthreads();
        s[threadIdx.x] += t;
        __syncthreads();
    }
    if (i < N) inc[i] = s[threadIdx.x];
    if (threadIdx.x == 255) bsum[blockIdx.x] = s[255];
}
__global__ void scan2_kernel(int* bsum, int nb) {
    __shared__ int s[512];
    __shared__ int carry;
    if (threadIdx.x == 0) carry = 0;
    __syncthreads();
    for (int base = 0; base < nb; base += 512) {
        const int i = base + threadIdx.x;
        s[threadIdx.x] = (i < nb) ? bsum[i] : 0;
        __syncthreads();
#pragma unroll
        for (int off = 1; off < 512; off <<= 1) {
            int t = (threadIdx.x >= off) ? s[threadIdx.x - off] : 0;
            __syncthreads();
            s[threadIdx.x] += t;
            __syncthreads();
        }
        const int c = carry;
        if (i < nb) bsum[i] = s[threadIdx.x] + c;
        __syncthreads();
        if (threadIdx.x == 511) carry = c + s[511];
        __syncthreads();
    }
}
__global__ void scan3_kernel(const int* __restrict__ inc, const int* __restrict__ degi,
                             const int* __restrict__ bsum, int* __restrict__ rowptr,
                             int* __restrict__ rp2, int N) {
    const int i = blockIdx.x * 256 + threadIdx.x;
    if (i >= N) return;
    const int prev = (blockIdx.x > 0) ? bsum[blockIdx.x - 1] : 0;
    const int rp = prev + inc[i] - degi[i];   // exclusive prefix
    rowptr[i] = rp;
    rp2[i]    = rp;
}
__global__ void fill_kernel(const int* __restrict__ src, const int* __restrict__ dst,
                            int* rp2, const float* __restrict__ dinv,
                            int* __restrict__ csr_src, float* __restrict__ csr_norm,
                            int2* __restrict__ csr_pk, int E) {
    const int e = blockIdx.x * 256 + threadIdx.x;
    if (e >= E) return;
    const int s = src[e], d = dst[e];
    const int pos = atomicAdd(&rp2[d], 1);
    const float nm = dinv[s] * dinv[d];
    csr_src[pos]  = s;
    csr_norm[pos] = nm;
    csr_pk[pos]   = make_int2(s, __float_as_int(nm));
}

// ---------------------------------------------------------------------------
// Standalone gather (fallback path for small ws / column passes)
// ---------------------------------------------------------------------------
template<typename OT>
__global__ __launch_bounds__(256) void gather_kernel(
    const bf16* __restrict__ xwb,
    const int* __restrict__ rowptr, const int* __restrict__ degi,
    const int* __restrict__ csr_src, const float* __restrict__ csr_norm,
    const float* __restrict__ dinv, const float* __restrict__ bias,
    OT* __restrict__ out, int N, int colbase, int cw, int lg)
{
    const long tid = (long)blockIdx.x * 256 + threadIdx.x;
    const long d = tid >> lg;
    const int  c = (int)(tid & ((1 << lg) - 1));
    if (d >= N) return;

    const int start = rowptr[d];
    const int deg   = degi[d];
    const int h     = deg >> 1;
    const bf16* xb  = xwb + c * 8;

    float acca[8] = {0.f, 0.f, 0.f, 0.f, 0.f, 0.f, 0.f, 0.f};
    float accb[8] = {0.f, 0.f, 0.f, 0.f, 0.f, 0.f, 0.f, 0.f};
    for (int k = 0; k < h; ++k) {
        const int   sa = csr_src[start + k];
        const int   sb = csr_src[start + h + k];
        const float na = csr_norm[start + k];
        const float nb_ = csr_norm[start + h + k];
        bf16x8 va = *(const bf16x8*)(xb + (long)sa * cw);
        bf16x8 vb = *(const bf16x8*)(xb + (long)sb * cw);
#pragma unroll
        for (int j = 0; j < 8; ++j) {
            acca[j] += (float)va[j] * na;
            accb[j] += (float)vb[j] * nb_;
        }
    }
    if (deg & 1) {
        const int   s  = csr_src[start + deg - 1];
        const float nm = csr_norm[start + deg - 1];
        bf16x8 v = *(const bf16x8*)(xb + (long)s * cw);
#pragma unroll
        for (int j = 0; j < 8; ++j) acca[j] += (float)v[j] * nm;
    }

    const float di = dinv[d], sl = di * di;
    bf16x8 vd = *(const bf16x8*)(xb + d * cw);
    const int col = colbase + c * 8;
    float v[8];
#pragma unroll
    for (int j = 0; j < 8; ++j) {
        float t = acca[j] + accb[j] + (float)vd[j] * sl + bias[col + j];
        v[j] = (t >= 0.f) ? t : 0.01f * t;
    }
    if constexpr (std::is_same<OT, bf16>::value) {
        bf16x8 o;
#pragma unroll
        for (int j = 0; j < 8; ++j) o[j] = (bf16)v[j];
        *(bf16x8*)(out + d * 128 + col) = o;
    } else {
        f32x4 o0, o1;
#pragma unroll
        for (int j = 0; j < 4; ++j) { o0[j] = v[j]; o1[j] = v[4 + j]; }
        *(f32x4*)(out + d * 128 + col)     = o0;
        *(f32x4*)(out + d * 128 + col + 4) = o1;
    }
}

// ---------------------------------------------------------------------------
// LP head: 16 lanes per edge, shfl reduce.
// ---------------------------------------------------------------------------
__global__ __launch_bounds__(256) void lp_kernel(
    const float* __restrict__ emb, const int* __restrict__ eli,
    const float* __restrict__ wpost, const float* __restrict__ bpost,
    float* __restrict__ logits, int EL)
{
    const long t = (long)blockIdx.x * 256 + threadIdx.x;
    const long e = t >> 4;
    const int  c = (int)(t & 15);
    if (e >= EL) return;
    const long s = eli[e], d = eli[EL + e];

    f32x4 a0 = *(const f32x4*)(emb + s * 128 + c * 8);
    f32x4 a1 = *(const f32x4*)(emb + s * 128 + c * 8 + 4);
    f32x4 b0 = *(const f32x4*)(emb + d * 128 + c * 8);
    f32x4 b1 = *(const f32x4*)(emb + d * 128 + c * 8 + 4);
    f32x4 w00 = *(const f32x4*)(wpost + c * 8);
    f32x4 w01 = *(const f32x4*)(wpost + c * 8 + 4);
    f32x4 w10 = *(const f32x4*)(wpost + 128 + c * 8);
    f32x4 w11 = *(const f32x4*)(wpost + 128 + c * 8 + 4);

    float acc = 0.f;
#pragma unroll
    for (int i = 0; i < 4; ++i) {
        acc += a0[i] * b0[i] * (w00[i] + w10[i]);
        acc += a1[i] * b1[i] * (w01[i] + w11[i]);
    }
#pragma unroll
    for (int m = 1; m < 16; m <<= 1) acc += __shfl_xor(acc, m);
    if (c == 0) logits[e] = acc + bpost[0] + bpost[1];
}

// ---------------------------------------------------------------------------
extern "C" void kernel_launch(void* const* d_in, const int* in_sizes, int n_in,
                              void* d_out, int out_size, void* d_ws, size_t ws_size,
                              hipStream_t stream) {
    const float* x      = (const float*)d_in[0];
    const int*   ei     = (const int*)d_in[1];   // [2,E]: row0=src, row1=dst
    const int*   eli    = (const int*)d_in[2];
    const float* prev0  = (const float*)d_in[3];
    const float* prev1  = (const float*)d_in[4];
    const float* w_pre1 = (const float*)d_in[5];
    const float* b_pre1 = (const float*)d_in[6];
    const float* w_pre2 = (const float*)d_in[7];
    const float* b_pre2 = (const float*)d_in[8];
    const float* w_c1   = (const float*)d_in[9];
    const float* b_c1   = (const float*)d_in[10];
    const float* w_c2   = (const float*)d_in[11];
    const float* b_c2   = (const float*)d_in[12];
    const float* w_post = (const float*)d_in[13];
    const float* b_post = (const float*)d_in[14];
    const float* g1_wih = (const float*)d_in[15];
    const float* g1_whh = (const float*)d_in[16];
    const float* g1_bih = (const float*)d_in[17];
    const float* g1_bhh = (const float*)d_in[18];
    const float* g2_wih = (const float*)d_in[19];
    const float* g2_whh = (const float*)d_in[20];
    const float* g2_bih = (const float*)d_in[21];
    const float* g2_bhh = (const float*)d_in[22];

    const int N  = in_sizes[0] / 128;
    const int E  = in_sizes[1] / 2;
    const int EL = in_sizes[2] / 2;
    const long NH = (long)N * 128;

    // outputs (f32)
    float* out    = (float*)d_out;
    float* logits = out;
    float* emb0   = out + EL;
    float* emb1   = emb0 + NH;
    float* emb2   = emb1 + NH;

    // bf16 intermediates in currently-dead output slots
    bf16* H1b = (bf16*)emb1;   // [N,256] bf16 == emb1 slot
    bf16* H2b = (bf16*)emb2;   // [N,128] bf16 (first half of emb2 slot)
    bf16* h1b = (bf16*)emb2;   // fallback only

    // ---- workspace layout ----
    char* ws = (char*)d_ws;
    size_t p = 0;
    auto alloc = [&](size_t bytes) { size_t o = p; p = (p + bytes + 255) & ~(size_t)255; return o; };
    float* dinv    = (float*)(ws + alloc((size_t)N * 4));
    int*   degi    = (int*)  (ws + alloc((size_t)N * 4));
    int*   inc     = (int*)  (ws + alloc((size_t)N * 4));
    int*   rowptr  = (int*)  (ws + alloc((size_t)(N + 1) * 4));
    int*   rp2     = (int*)  (ws + alloc((size_t)N * 4));
    int*   bsum    = (int*)  (ws + alloc(4096));
    bf16*  wb      = (bf16*) (ws + alloc((size_t)294912 * 2));
    int*   csr_src = (int*)  (ws + alloc((size_t)E * 4));
    float* csr_nrm = (float*)(ws + alloc((size_t)E * 4));
    int2*  csr_pk  = (int2*) (ws + alloc((size_t)E * 8));
    const size_t fixed = p;
    bf16*  xwb     = (bf16*)(ws + fixed);

    int cw = 128;
    while (cw > 16 && fixed + (size_t)N * cw * 2 > ws_size) cw >>= 1;
    const int lg = __builtin_ctz(cw >> 3);
    const int passes = 128 / cw;
    const bool fused = (cw == 128);
    const bool big_ws = fused &&
        (ws_size >= fixed + (size_t)N * 128 * 2 + (size_t)N * 128 * 2);
    bf16* h2b = big_ws ? (bf16*)(ws + fixed + (size_t)N * 128 * 2) : nullptr;

    bf16* wb_pre1 = wb;
    bf16* wb_pre2 = wb_pre1 + 32768;
    bf16* wb_c1   = wb_pre2 + 32768;
    bf16* wb_c2   = wb_c1 + 16384;
    bf16* wb_g1i  = wb_c2 + 16384;
    bf16* wb_g1h  = wb_g1i + 49152;
    bf16* wb_g2i  = wb_g1h + 49152;
    bf16* wb_g2h  = wb_g2i + 49152;

    const int gB = 256;
    const dim3 blk(gB);
    const int grid_rows128 = (N + 127) / 128;
    const int grid_gru     = (N + 63) / 64;
    const int grid_E       = (E + gB - 1) / gB;
    const int nb           = (N + 255) / 256;

    cvt8_kernel<<<(294912 + 255) / 256, blk, 0, stream>>>(
        w_pre1, w_pre2, w_c1, w_c2, g1_wih, g1_whh, g2_wih, g2_whh, wb);

    // ---- CSR build ----
    hipMemsetAsync(degi, 0, (size_t)N * 4, stream);
    deg_kernel<<<grid_E, blk, 0, stream>>>(ei + E, degi, E);
    scan1_kernel<<<nb, blk, 0, stream>>>(degi, inc, bsum, dinv, N);
    scan2_kernel<<<1, 512, 0, stream>>>(bsum, nb);
    scan3_kernel<<<nb, blk, 0, stream>>>(inc, degi, bsum, rowptr, rp2, N);
    fill_kernel<<<grid_E, blk, 0, stream>>>(ei, ei + E, rp2, dinv, csr_src, csr_nrm, csr_pk, E);

    // ---- preprocess: x -> H1b (bf16) -> H2b (bf16) ----
    gemm_kernel<128, 256, true, true, float, bf16><<<grid_rows128, blk, 0, stream>>>(x, wb_pre1, b_pre1, H1b, N);
    gemm_kernel<256, 128, true, true, bf16,  bf16><<<grid_rows128, blk, 0, stream>>>(H1b, wb_pre2, b_pre2, H2b, N);

    // GRU1: emb0 = gru(H2b, prev0)
    gru_kernel<bf16><<<grid_gru, blk, 0, stream>>>(H2b, prev0, wb_g1i, wb_g1h, g1_bih, g1_bhh, emb0, N);

    auto run_gemm = [&](const float* hin, const bf16* wp) {
        switch (cw) {
        case 128: gemm_kernel<128, 128, false, false, float, bf16><<<grid_rows128, blk, 0, stream>>>(hin, wp, nullptr, xwb, N); break;
        case 64:  gemm_kernel<128, 64,  false, false, float, bf16><<<grid_rows128, blk, 0, stream>>>(hin, wp, nullptr, xwb, N); break;
        case 32:  gemm_kernel<128, 32,  false, false, float, bf16><<<grid_rows128, blk, 0, stream>>>(hin, wp, nullptr, xwb, N); break;
        default:  gemm_kernel<128, 16,  false, false, float, bf16><<<grid_rows128, blk, 0, stream>>>(hin, wp, nullptr, xwb, N); break;
        }
    };

    if (fused) {
        // conv1 + GRU2 fused: emb0 -> xwb -> (gather+gru) -> emb1
        run_gemm(emb0, wb_c1);
        gg_kernel<<<grid_gru, blk, 0, stream>>>(xwb, rowptr, degi, csr_pk,
                                                dinv, b_c1, prev0,
                                                wb_g1i, wb_g1h, g1_bih, g1_bhh, emb1, N);
        // conv2 + GRU3 fused: emb1 -> xwb -> (gather+gru) -> emb2
        run_gemm(emb1, wb_c2);
        gg_kernel<<<grid_gru, blk, 0, stream>>>(xwb, rowptr, degi, csr_pk,
                                                dinv, b_c2, prev1,
                                                wb_g2i, wb_g2h, g2_bih, g2_bhh, emb2, N);
    } else {
        const int grid_ga = (int)((((long)N << lg) + gB - 1) / gB);
        for (int ps = 0; ps < passes; ++ps) {
            run_gemm(emb0, wb_c1 + (size_t)(ps * cw) * 128);
            gather_kernel<bf16><<<grid_ga, blk, 0, stream>>>(xwb, rowptr, degi, csr_src, csr_nrm,
                                                             dinv, b_c1, h1b, N, ps * cw, cw, lg);
        }
        gru_kernel<bf16><<<grid_gru, blk, 0, stream>>>(h1b, prev0, wb_g1i, wb_g1h, g1_bih, g1_bhh, emb1, N);
        for (int ps = 0; ps < passes; ++ps) {
            run_gemm(emb1, wb_c2 + (size_t)(ps * cw) * 128);
            if (big_ws)
                gather_kernel<bf16><<<grid_ga, blk, 0, stream>>>(xwb, rowptr, degi, csr_src, csr_nrm,
                                                                 dinv, b_c2, h2b, N, ps * cw, cw, lg);
            else
                gather_kernel<float><<<grid_ga, blk, 0, stream>>>(xwb, rowptr, degi, csr_src, csr_nrm,
                                                                  dinv, b_c2, emb2, N, ps * cw, cw, lg);
        }
        if (big_ws)
            gru_kernel<bf16><<<grid_gru, blk, 0, stream>>>(h2b, prev1, wb_g2i, wb_g2h, g2_bih, g2_bhh, emb2, N);
        else
            gru_kernel<float><<<grid_gru, blk, 0, stream>>>(emb2, prev1, wb_g2i, wb_g2h, g2_bih, g2_bhh, emb2, N);
    }

    // LP head (16 lanes/edge)
    lp_kernel<<<(int)(((long)EL * 16 + gB - 1) / gB), blk, 0, stream>>>(emb2, eli, w_post, b_post, logits, EL);
}